// Round 1
// baseline (1775.698 us; speedup 1.0000x reference)
//
#include <hip/hip_runtime.h>

#define D 64

// cur = concat(user, item); out(=sum accumulator) = same (layer-0 embedding)
__global__ void lg_init(const float4* __restrict__ user, const float4* __restrict__ item,
                        float4* __restrict__ cur, float4* __restrict__ sum,
                        int user_vec4, int total_vec4) {
    int i = blockIdx.x * blockDim.x + threadIdx.x;
    if (i >= total_vec4) return;
    float4 v = (i < user_vec4) ? user[i] : item[i - user_vec4];
    cur[i] = v;
    sum[i] = v;
}

// Edge-parallel SpMM scatter: 64 lanes per edge, lane d handles dim d.
// next[rows[e]*D + d] += vals[e] * cur[cols[e]*D + d]
__global__ void lg_scatter(const int* __restrict__ rows, const int* __restrict__ cols,
                           const float* __restrict__ vals,
                           const float* __restrict__ cur, float* __restrict__ next,
                           int nnz) {
    int gid = blockIdx.x * blockDim.x + threadIdx.x;
    int e = gid >> 6;
    int d = gid & 63;
    if (e >= nnz) return;
    int r = rows[e];
    int c = cols[e];
    float v = vals[e];
    atomicAdd(&next[r * D + d], v * cur[c * D + d]);
}

// Per-row L2 normalize (in place, so buffer doubles as next layer's input)
// and accumulate into sum.
__global__ void lg_norm_acc(float* __restrict__ emb, float* __restrict__ sum, int n) {
    int row = blockIdx.x * (blockDim.x >> 6) + (threadIdx.x >> 6);
    int d = threadIdx.x & 63;
    if (row >= n) return;
    int idx = row * D + d;
    float v = emb[idx];
    float ss = v * v;
    #pragma unroll
    for (int off = 32; off > 0; off >>= 1) ss += __shfl_xor(ss, off, 64);
    float nrm = sqrtf(ss);
    float out = v / fmaxf(nrm, 1e-12f);
    emb[idx] = out;
    sum[idx] += out;
}

// out = sum / 4 (mean over 4 layer embeddings), in place
__global__ void lg_final(float4* __restrict__ out, int n4) {
    int i = blockIdx.x * blockDim.x + threadIdx.x;
    if (i >= n4) return;
    float4 s = out[i];
    out[i] = make_float4(s.x * 0.25f, s.y * 0.25f, s.z * 0.25f, s.w * 0.25f);
}

extern "C" void kernel_launch(void* const* d_in, const int* in_sizes, int n_in,
                              void* d_out, int out_size, void* d_ws, size_t ws_size,
                              hipStream_t stream) {
    const float* user = (const float*)d_in[0];
    const float* item = (const float*)d_in[1];
    const float* vals = (const float*)d_in[2];
    const int*   rows = (const int*)d_in[3];
    const int*   cols = (const int*)d_in[4];

    const int nU  = in_sizes[0] / D;
    const int nI  = in_sizes[1] / D;
    const int N   = nU + nI;
    const int nnz = in_sizes[2];

    const size_t embElems = (size_t)N * D;
    float* buf0 = (float*)d_ws;
    float* buf1 = buf0 + embElems;
    float* sum  = (float*)d_out;   // accumulate layer outputs directly in d_out

    const int total4 = (int)(embElems / 4);
    lg_init<<<(total4 + 255) / 256, 256, 0, stream>>>(
        (const float4*)user, (const float4*)item,
        (float4*)buf0, (float4*)sum, nU * D / 4, total4);

    float* cur = buf0;
    float* nxt = buf1;
    for (int layer = 0; layer < 3; ++layer) {
        hipMemsetAsync(nxt, 0, embElems * sizeof(float), stream);
        int totThreads = nnz * 64;           // 153.6M < 2^31, fits int
        int blocks = (totThreads + 255) / 256;
        lg_scatter<<<blocks, 256, 0, stream>>>(rows, cols, vals, cur, nxt, nnz);
        lg_norm_acc<<<(N + 3) / 4, 256, 0, stream>>>(nxt, sum, N);
        float* t = cur; cur = nxt; nxt = t;
    }

    lg_final<<<(total4 + 255) / 256, 256, 0, stream>>>((float4*)sum, total4);
}

// Round 2
// 1032.251 us; speedup vs baseline: 1.7202x; 1.7202x over previous
//
#include <hip/hip_runtime.h>

#define D 64

// ---------------- shared init/final ----------------

// cur = concat(user, item); sum(=d_out accumulator) = same (layer-0 embedding)
__global__ void lg_init(const float4* __restrict__ user, const float4* __restrict__ item,
                        float4* __restrict__ cur, float4* __restrict__ sum,
                        int user_vec4, int total_vec4) {
    int i = blockIdx.x * blockDim.x + threadIdx.x;
    if (i >= total_vec4) return;
    float4 v = (i < user_vec4) ? user[i] : item[i - user_vec4];
    cur[i] = v;
    sum[i] = v;
}

// out = sum / 4 (mean over 4 layer embeddings), in place
__global__ void lg_final(float4* __restrict__ out, int n4) {
    int i = blockIdx.x * blockDim.x + threadIdx.x;
    if (i >= n4) return;
    float4 s = out[i];
    out[i] = make_float4(s.x * 0.25f, s.y * 0.25f, s.z * 0.25f, s.w * 0.25f);
}

// ---------------- CSR build (counting sort by row) ----------------

__global__ void lg_hist(const int* __restrict__ rows, int* __restrict__ counts, int nnz) {
    int e = blockIdx.x * blockDim.x + threadIdx.x;
    if (e >= nnz) return;
    atomicAdd(&counts[rows[e]], 1);
}

// Single-block chunked exclusive scan: counts[0..n) -> offsets[0..n], cursor copy.
// 1024 threads, each scans a contiguous chunk; Hillis-Steele over chunk totals.
__global__ void lg_scan(const int* __restrict__ counts, int* __restrict__ offsets,
                        int* __restrict__ cursor, int n) {
    const int T = 1024;
    int t = threadIdx.x;
    int chunk = (n + T - 1) / T;
    int start = t * chunk;
    int end = min(start + chunk, n);
    int sum = 0;
    for (int i = start; i < end; ++i) sum += counts[i];
    __shared__ int sdata[T];
    sdata[t] = sum;
    __syncthreads();
    #pragma unroll
    for (int off = 1; off < T; off <<= 1) {
        int v = (t >= off) ? sdata[t - off] : 0;
        __syncthreads();
        sdata[t] += v;
        __syncthreads();
    }
    int offset = sdata[t] - sum;   // exclusive prefix for this chunk
    for (int i = start; i < end; ++i) {
        int c = counts[i];
        offsets[i] = offset;
        cursor[i] = offset;
        offset += c;
    }
    if (t == T - 1) offsets[n] = sdata[T - 1];
}

__global__ void lg_fill(const int* __restrict__ rows, const int* __restrict__ cols,
                        const float* __restrict__ vals, int* __restrict__ cursor,
                        int* __restrict__ csr_col, float* __restrict__ csr_val, int nnz) {
    int e = blockIdx.x * blockDim.x + threadIdx.x;
    if (e >= nnz) return;
    int r = rows[e];
    int pos = atomicAdd(&cursor[r], 1);
    csr_col[pos] = cols[e];
    csr_val[pos] = vals[e];
}

// ---------------- pull SpMM + fused L2-normalize + layer-sum ----------------
// One wave (64 lanes) per row; lane d owns dim d.
__global__ void lg_pull(const int* __restrict__ offs, const int* __restrict__ csr_col,
                        const float* __restrict__ csr_val,
                        const float* __restrict__ cur, float* __restrict__ nxt,
                        float* __restrict__ sum, int n) {
    int row = blockIdx.x * (blockDim.x >> 6) + (threadIdx.x >> 6);
    int d = threadIdx.x & 63;
    if (row >= n) return;
    int beg = offs[row];
    int end = offs[row + 1];
    float acc = 0.f;
    int j = beg;
    for (; j + 4 <= end; j += 4) {
        int c0 = csr_col[j];     int c1 = csr_col[j + 1];
        int c2 = csr_col[j + 2]; int c3 = csr_col[j + 3];
        float v0 = csr_val[j];     float v1 = csr_val[j + 1];
        float v2 = csr_val[j + 2]; float v3 = csr_val[j + 3];
        float g0 = cur[(size_t)c0 * D + d];
        float g1 = cur[(size_t)c1 * D + d];
        float g2 = cur[(size_t)c2 * D + d];
        float g3 = cur[(size_t)c3 * D + d];
        acc += v0 * g0 + v1 * g1 + v2 * g2 + v3 * g3;
    }
    for (; j < end; ++j)
        acc += csr_val[j] * cur[(size_t)csr_col[j] * D + d];

    // fused L2 normalize across the wave (row fully resident)
    float ss = acc * acc;
    #pragma unroll
    for (int off = 32; off > 0; off >>= 1) ss += __shfl_xor(ss, off, 64);
    float out = acc / fmaxf(sqrtf(ss), 1e-12f);
    size_t idx = (size_t)row * D + d;
    nxt[idx] = out;
    sum[idx] += out;
}

// ---------------- fallback (R1 atomic-scatter path) ----------------

__global__ void lg_scatter(const int* __restrict__ rows, const int* __restrict__ cols,
                           const float* __restrict__ vals,
                           const float* __restrict__ cur, float* __restrict__ next,
                           int nnz) {
    int gid = blockIdx.x * blockDim.x + threadIdx.x;
    int e = gid >> 6;
    int d = gid & 63;
    if (e >= nnz) return;
    atomicAdd(&next[rows[e] * D + d], vals[e] * cur[cols[e] * D + d]);
}

__global__ void lg_norm_acc(float* __restrict__ emb, float* __restrict__ sum, int n) {
    int row = blockIdx.x * (blockDim.x >> 6) + (threadIdx.x >> 6);
    int d = threadIdx.x & 63;
    if (row >= n) return;
    int idx = row * D + d;
    float v = emb[idx];
    float ss = v * v;
    #pragma unroll
    for (int off = 32; off > 0; off >>= 1) ss += __shfl_xor(ss, off, 64);
    float out = v / fmaxf(sqrtf(ss), 1e-12f);
    emb[idx] = out;
    sum[idx] += out;
}

// ---------------- launch ----------------

extern "C" void kernel_launch(void* const* d_in, const int* in_sizes, int n_in,
                              void* d_out, int out_size, void* d_ws, size_t ws_size,
                              hipStream_t stream) {
    const float* user = (const float*)d_in[0];
    const float* item = (const float*)d_in[1];
    const float* vals = (const float*)d_in[2];
    const int*   rows = (const int*)d_in[3];
    const int*   cols = (const int*)d_in[4];

    const int nU  = in_sizes[0] / D;
    const int nI  = in_sizes[1] / D;
    const int N   = nU + nI;
    const int nnz = in_sizes[2];

    const size_t embElems = (size_t)N * D;
    float* sum = (float*)d_out;
    const int total4 = (int)(embElems / 4);

    // ws layout
    char* p = (char*)d_ws;
    float* buf0 = (float*)p;                 p += embElems * sizeof(float);
    float* buf1 = (float*)p;                 p += embElems * sizeof(float);
    size_t baseBytes = (size_t)(p - (char*)d_ws);
    int*   counts  = (int*)p;                p += (size_t)N * sizeof(int);
    int*   offsets = (int*)p;                p += (size_t)(N + 1) * sizeof(int);
    int*   cursor  = (int*)p;                p += (size_t)N * sizeof(int);
    int*   csr_col = (int*)p;                p += (size_t)nnz * sizeof(int);
    float* csr_val = (float*)p;              p += (size_t)nnz * sizeof(float);
    size_t csrBytes = (size_t)(p - (char*)d_ws);

    lg_init<<<(total4 + 255) / 256, 256, 0, stream>>>(
        (const float4*)user, (const float4*)item,
        (float4*)buf0, (float4*)sum, nU * D / 4, total4);

    if (ws_size >= csrBytes) {
        // ---- CSR build ----
        hipMemsetAsync(counts, 0, (size_t)N * sizeof(int), stream);
        int eb = (nnz + 255) / 256;
        lg_hist<<<eb, 256, 0, stream>>>(rows, counts, nnz);
        lg_scan<<<1, 1024, 0, stream>>>(counts, offsets, cursor, N);
        lg_fill<<<eb, 256, 0, stream>>>(rows, cols, vals, cursor, csr_col, csr_val, nnz);

        // ---- 3 layers of pull SpMM + fused normalize/accumulate ----
        float* cur = buf0;
        float* nxt = buf1;
        int rb = (N + 3) / 4;   // 4 rows per 256-thread block
        for (int layer = 0; layer < 3; ++layer) {
            lg_pull<<<rb, 256, 0, stream>>>(offsets, csr_col, csr_val, cur, nxt, sum, N);
            float* t = cur; cur = nxt; nxt = t;
        }
    } else {
        // ---- fallback: atomic scatter path (R1) ----
        (void)baseBytes;
        float* cur = buf0;
        float* nxt = buf1;
        for (int layer = 0; layer < 3; ++layer) {
            hipMemsetAsync(nxt, 0, embElems * sizeof(float), stream);
            int totThreads = nnz * 64;
            int blocks = (totThreads + 255) / 256;
            lg_scatter<<<blocks, 256, 0, stream>>>(rows, cols, vals, cur, nxt, nnz);
            lg_norm_acc<<<(N + 3) / 4, 256, 0, stream>>>(nxt, sum, N);
            float* t = cur; cur = nxt; nxt = t;
        }
    }

    lg_final<<<(total4 + 255) / 256, 256, 0, stream>>>((float4*)sum, total4);
}

// Round 3
// 748.318 us; speedup vs baseline: 2.3729x; 1.3794x over previous
//
#include <hip/hip_runtime.h>

#define D 64
#define SCAN_CHUNK 1024   // elements per block in the device-wide scan

static inline char* align16(char* p) {
    return (char*)(((uintptr_t)p + 15) & ~(uintptr_t)15);
}

// ---------------- shared init/final ----------------

__global__ void lg_init(const float4* __restrict__ user, const float4* __restrict__ item,
                        float4* __restrict__ cur, float4* __restrict__ sum,
                        int user_vec4, int total_vec4) {
    int i = blockIdx.x * blockDim.x + threadIdx.x;
    if (i >= total_vec4) return;
    float4 v = (i < user_vec4) ? user[i] : item[i - user_vec4];
    cur[i] = v;
    sum[i] = v;
}

__global__ void lg_final(float4* __restrict__ out, int n4) {
    int i = blockIdx.x * blockDim.x + threadIdx.x;
    if (i >= n4) return;
    float4 s = out[i];
    out[i] = make_float4(s.x * 0.25f, s.y * 0.25f, s.z * 0.25f, s.w * 0.25f);
}

// ---------------- CSR build ----------------

__global__ void lg_hist(const int* __restrict__ rows, int* __restrict__ counts, int nnz) {
    int e = blockIdx.x * blockDim.x + threadIdx.x;
    if (e >= nnz) return;
    atomicAdd(&counts[rows[e]], 1);
}

// Pass 1: per-block sums of SCAN_CHUNK counts (coalesced).
__global__ void lg_scan_reduce(const int* __restrict__ counts, int* __restrict__ partials, int n) {
    __shared__ int s[256];
    int base = blockIdx.x * SCAN_CHUNK;
    int sum = 0;
    for (int i = threadIdx.x; i < SCAN_CHUNK; i += 256) {
        int idx = base + i;
        if (idx < n) sum += counts[idx];
    }
    // wave reduce then LDS
    #pragma unroll
    for (int off = 32; off > 0; off >>= 1) sum += __shfl_xor(sum, off, 64);
    if ((threadIdx.x & 63) == 0) s[threadIdx.x >> 6] = sum;
    __syncthreads();
    if (threadIdx.x == 0) {
        int tot = s[0] + s[1] + s[2] + s[3];
        partials[blockIdx.x] = tot;
    }
}

// Pass 2: single small block: exclusive scan of nb (<=256) partials; write total to offsets[n].
__global__ void lg_scan_partials(int* __restrict__ partials, int nb, int* __restrict__ offsets_end) {
    __shared__ int s[256];
    int t = threadIdx.x;
    int v = (t < nb) ? partials[t] : 0;
    s[t] = v;
    __syncthreads();
    #pragma unroll
    for (int off = 1; off < 256; off <<= 1) {
        int x = (t >= off) ? s[t - off] : 0;
        __syncthreads();
        s[t] += x;
        __syncthreads();
    }
    if (t < nb) partials[t] = s[t] - v;   // exclusive
    if (t == 255) *offsets_end = s[255];  // grand total
}

// Pass 3: final exclusive scan; each thread owns 4 consecutive counts (int4).
__global__ void lg_scan_final(const int* __restrict__ counts, const int* __restrict__ partials,
                              int* __restrict__ offsets, int* __restrict__ cursor, int n) {
    __shared__ int s[256];
    int t = threadIdx.x;
    int base = blockIdx.x * SCAN_CHUNK + t * 4;
    int4 c = make_int4(0, 0, 0, 0);
    if (base + 3 < n) {
        c = *(const int4*)(counts + base);
    } else {
        if (base     < n) c.x = counts[base];
        if (base + 1 < n) c.y = counts[base + 1];
        if (base + 2 < n) c.z = counts[base + 2];
        if (base + 3 < n) c.w = counts[base + 3];
    }
    int tsum = c.x + c.y + c.z + c.w;
    s[t] = tsum;
    __syncthreads();
    #pragma unroll
    for (int off = 1; off < 256; off <<= 1) {
        int x = (t >= off) ? s[t - off] : 0;
        __syncthreads();
        s[t] += x;
        __syncthreads();
    }
    int excl = s[t] - tsum + partials[blockIdx.x];
    int4 o;
    o.x = excl;
    o.y = o.x + c.x;
    o.z = o.y + c.y;
    o.w = o.z + c.z;
    if (base + 3 < n) {
        *(int4*)(offsets + base) = o;
        *(int4*)(cursor + base) = o;
    } else {
        if (base     < n) { offsets[base]     = o.x; cursor[base]     = o.x; }
        if (base + 1 < n) { offsets[base + 1] = o.y; cursor[base + 1] = o.y; }
        if (base + 2 < n) { offsets[base + 2] = o.z; cursor[base + 2] = o.z; }
        if (base + 3 < n) { offsets[base + 3] = o.w; cursor[base + 3] = o.w; }
    }
}

// Fallback single-block scan (only if N > 256*SCAN_CHUNK).
__global__ void lg_scan1(const int* __restrict__ counts, int* __restrict__ offsets,
                         int* __restrict__ cursor, int n) {
    const int T = 1024;
    int t = threadIdx.x;
    int chunk = (n + T - 1) / T;
    int start = t * chunk;
    int end = min(start + chunk, n);
    int sum = 0;
    for (int i = start; i < end; ++i) sum += counts[i];
    __shared__ int sdata[T];
    sdata[t] = sum;
    __syncthreads();
    #pragma unroll
    for (int off = 1; off < T; off <<= 1) {
        int v = (t >= off) ? sdata[t - off] : 0;
        __syncthreads();
        sdata[t] += v;
        __syncthreads();
    }
    int offset = sdata[t] - sum;
    for (int i = start; i < end; ++i) {
        int c = counts[i];
        offsets[i] = offset;
        cursor[i] = offset;
        offset += c;
    }
    if (t == T - 1) offsets[n] = sdata[T - 1];
}

// Fill interleaved edge array: edges[pos] = {col, val_bits}
__global__ void lg_fill(const int* __restrict__ rows, const int* __restrict__ cols,
                        const float* __restrict__ vals, int* __restrict__ cursor,
                        int2* __restrict__ edges, int nnz) {
    int e = blockIdx.x * blockDim.x + threadIdx.x;
    if (e >= nnz) return;
    int pos = atomicAdd(&cursor[rows[e]], 1);
    edges[pos] = make_int2(cols[e], __float_as_int(vals[e]));
}

// ---------------- pull SpMM + fused L2-normalize + layer-sum ----------------
// One wave per row; lane d owns dim d.
__global__ void lg_pull(const int* __restrict__ offs, const int2* __restrict__ edges,
                        const float* __restrict__ cur, float* __restrict__ nxt,
                        float* __restrict__ sum, int n) {
    int row = blockIdx.x * (blockDim.x >> 6) + (threadIdx.x >> 6);
    int d = threadIdx.x & 63;
    if (row >= n) return;
    int beg = offs[row];
    int end = offs[row + 1];
    float acc = 0.f;
    int j = beg;
    for (; j + 4 <= end; j += 4) {
        int2 e0 = edges[j];     int2 e1 = edges[j + 1];
        int2 e2 = edges[j + 2]; int2 e3 = edges[j + 3];
        float g0 = cur[(size_t)e0.x * D + d];
        float g1 = cur[(size_t)e1.x * D + d];
        float g2 = cur[(size_t)e2.x * D + d];
        float g3 = cur[(size_t)e3.x * D + d];
        acc += __int_as_float(e0.y) * g0 + __int_as_float(e1.y) * g1
             + __int_as_float(e2.y) * g2 + __int_as_float(e3.y) * g3;
    }
    for (; j < end; ++j) {
        int2 e = edges[j];
        acc += __int_as_float(e.y) * cur[(size_t)e.x * D + d];
    }

    float ss = acc * acc;
    #pragma unroll
    for (int off = 32; off > 0; off >>= 1) ss += __shfl_xor(ss, off, 64);
    float out = acc / fmaxf(sqrtf(ss), 1e-12f);
    size_t idx = (size_t)row * D + d;
    nxt[idx] = out;
    sum[idx] += out;
}

// ---------------- fallback (atomic-scatter path) ----------------

__global__ void lg_scatter(const int* __restrict__ rows, const int* __restrict__ cols,
                           const float* __restrict__ vals,
                           const float* __restrict__ cur, float* __restrict__ next,
                           int nnz) {
    int gid = blockIdx.x * blockDim.x + threadIdx.x;
    int e = gid >> 6;
    int d = gid & 63;
    if (e >= nnz) return;
    atomicAdd(&next[rows[e] * D + d], vals[e] * cur[cols[e] * D + d]);
}

__global__ void lg_norm_acc(float* __restrict__ emb, float* __restrict__ sum, int n) {
    int row = blockIdx.x * (blockDim.x >> 6) + (threadIdx.x >> 6);
    int d = threadIdx.x & 63;
    if (row >= n) return;
    int idx = row * D + d;
    float v = emb[idx];
    float ss = v * v;
    #pragma unroll
    for (int off = 32; off > 0; off >>= 1) ss += __shfl_xor(ss, off, 64);
    float out = v / fmaxf(sqrtf(ss), 1e-12f);
    emb[idx] = out;
    sum[idx] += out;
}

// ---------------- launch ----------------

extern "C" void kernel_launch(void* const* d_in, const int* in_sizes, int n_in,
                              void* d_out, int out_size, void* d_ws, size_t ws_size,
                              hipStream_t stream) {
    const float* user = (const float*)d_in[0];
    const float* item = (const float*)d_in[1];
    const float* vals = (const float*)d_in[2];
    const int*   rows = (const int*)d_in[3];
    const int*   cols = (const int*)d_in[4];

    const int nU  = in_sizes[0] / D;
    const int nI  = in_sizes[1] / D;
    const int N   = nU + nI;
    const int nnz = in_sizes[2];

    const size_t embElems = (size_t)N * D;
    float* sum = (float*)d_out;
    const int total4 = (int)(embElems / 4);

    // ws layout (all 16B-aligned)
    char* p = (char*)d_ws;
    float* buf0 = (float*)p;      p = align16(p + embElems * sizeof(float));
    float* buf1 = (float*)p;      p = align16(p + embElems * sizeof(float));
    int* counts   = (int*)p;      p = align16(p + (size_t)N * sizeof(int));
    int* offsets  = (int*)p;      p = align16(p + (size_t)(N + 1) * sizeof(int));
    int* cursor   = (int*)p;      p = align16(p + (size_t)N * sizeof(int));
    int* partials = (int*)p;      p = align16(p + 256 * sizeof(int));
    int2* edges   = (int2*)p;     p = align16(p + (size_t)nnz * sizeof(int2));
    size_t csrBytes = (size_t)(p - (char*)d_ws);

    lg_init<<<(total4 + 255) / 256, 256, 0, stream>>>(
        (const float4*)user, (const float4*)item,
        (float4*)buf0, (float4*)sum, nU * D / 4, total4);

    if (ws_size >= csrBytes) {
        // ---- CSR build ----
        hipMemsetAsync(counts, 0, (size_t)N * sizeof(int), stream);
        int eb = (nnz + 255) / 256;
        lg_hist<<<eb, 256, 0, stream>>>(rows, counts, nnz);

        int nb = (N + SCAN_CHUNK - 1) / SCAN_CHUNK;
        if (nb <= 256) {
            lg_scan_reduce<<<nb, 256, 0, stream>>>(counts, partials, N);
            lg_scan_partials<<<1, 256, 0, stream>>>(partials, nb, offsets + N);
            lg_scan_final<<<nb, 256, 0, stream>>>(counts, partials, offsets, cursor, N);
        } else {
            lg_scan1<<<1, 1024, 0, stream>>>(counts, offsets, cursor, N);
        }
        lg_fill<<<eb, 256, 0, stream>>>(rows, cols, vals, cursor, edges, nnz);

        // ---- 3 layers of pull SpMM + fused normalize/accumulate ----
        float* cur = buf0;
        float* nxt = buf1;
        int rb = (N + 3) / 4;   // 4 rows (waves) per 256-thread block
        for (int layer = 0; layer < 3; ++layer) {
            lg_pull<<<rb, 256, 0, stream>>>(offsets, edges, cur, nxt, sum, N);
            float* t = cur; cur = nxt; nxt = t;
        }
    } else {
        // ---- fallback: atomic scatter path ----
        float* cur = buf0;
        float* nxt = buf1;
        for (int layer = 0; layer < 3; ++layer) {
            hipMemsetAsync(nxt, 0, embElems * sizeof(float), stream);
            int totThreads = nnz * 64;
            int blocks = (totThreads + 255) / 256;
            lg_scatter<<<blocks, 256, 0, stream>>>(rows, cols, vals, cur, nxt, nnz);
            lg_norm_acc<<<(N + 3) / 4, 256, 0, stream>>>(nxt, sum, N);
            float* t = cur; cur = nxt; nxt = t;
        }
    }

    lg_final<<<(total4 + 255) / 256, 256, 0, stream>>>((float4*)sum, total4);
}

// Round 4
// 690.158 us; speedup vs baseline: 2.5729x; 1.0843x over previous
//
#include <hip/hip_runtime.h>

#define D 64
#define SCAN_CHUNK 1024

static inline char* align16(char* p) {
    return (char*)(((uintptr_t)p + 15) & ~(uintptr_t)15);
}

// ---------------- init ----------------

// CSR path: only sum(=d_out) needs the layer-0 embedding.
__global__ void lg_init_sum(const float4* __restrict__ user, const float4* __restrict__ item,
                            float4* __restrict__ sum, int user_vec4, int total_vec4) {
    int i = blockIdx.x * blockDim.x + threadIdx.x;
    if (i >= total_vec4) return;
    sum[i] = (i < user_vec4) ? user[i] : item[i - user_vec4];
}

// Fallback path: needs cur too.
__global__ void lg_init(const float4* __restrict__ user, const float4* __restrict__ item,
                        float4* __restrict__ cur, float4* __restrict__ sum,
                        int user_vec4, int total_vec4) {
    int i = blockIdx.x * blockDim.x + threadIdx.x;
    if (i >= total_vec4) return;
    float4 v = (i < user_vec4) ? user[i] : item[i - user_vec4];
    cur[i] = v;
    sum[i] = v;
}

__global__ void lg_final(float4* __restrict__ out, int n4) {
    int i = blockIdx.x * blockDim.x + threadIdx.x;
    if (i >= n4) return;
    float4 s = out[i];
    out[i] = make_float4(s.x * 0.25f, s.y * 0.25f, s.z * 0.25f, s.w * 0.25f);
}

// ---------------- CSR build ----------------

__global__ void lg_hist(const int* __restrict__ rows, int* __restrict__ counts, int nnz) {
    int e = blockIdx.x * blockDim.x + threadIdx.x;
    if (e >= nnz) return;
    atomicAdd(&counts[rows[e]], 1);
}

__global__ void lg_scan_reduce(const int* __restrict__ counts, int* __restrict__ partials, int n) {
    __shared__ int s[4];
    int base = blockIdx.x * SCAN_CHUNK;
    int sum = 0;
    for (int i = threadIdx.x; i < SCAN_CHUNK; i += 256) {
        int idx = base + i;
        if (idx < n) sum += counts[idx];
    }
    #pragma unroll
    for (int off = 32; off > 0; off >>= 1) sum += __shfl_xor(sum, off, 64);
    if ((threadIdx.x & 63) == 0) s[threadIdx.x >> 6] = sum;
    __syncthreads();
    if (threadIdx.x == 0) partials[blockIdx.x] = s[0] + s[1] + s[2] + s[3];
}

__global__ void lg_scan_partials(int* __restrict__ partials, int nb, int* __restrict__ offsets_end) {
    __shared__ int s[256];
    int t = threadIdx.x;
    int v = (t < nb) ? partials[t] : 0;
    s[t] = v;
    __syncthreads();
    #pragma unroll
    for (int off = 1; off < 256; off <<= 1) {
        int x = (t >= off) ? s[t - off] : 0;
        __syncthreads();
        s[t] += x;
        __syncthreads();
    }
    if (t < nb) partials[t] = s[t] - v;
    if (t == 255) *offsets_end = s[255];
}

__global__ void lg_scan_final(const int* __restrict__ counts, const int* __restrict__ partials,
                              int* __restrict__ offsets, int* __restrict__ cursor, int n) {
    __shared__ int s[256];
    int t = threadIdx.x;
    int base = blockIdx.x * SCAN_CHUNK + t * 4;
    int4 c = make_int4(0, 0, 0, 0);
    if (base + 3 < n) {
        c = *(const int4*)(counts + base);
    } else {
        if (base     < n) c.x = counts[base];
        if (base + 1 < n) c.y = counts[base + 1];
        if (base + 2 < n) c.z = counts[base + 2];
        if (base + 3 < n) c.w = counts[base + 3];
    }
    int tsum = c.x + c.y + c.z + c.w;
    s[t] = tsum;
    __syncthreads();
    #pragma unroll
    for (int off = 1; off < 256; off <<= 1) {
        int x = (t >= off) ? s[t - off] : 0;
        __syncthreads();
        s[t] += x;
        __syncthreads();
    }
    int excl = s[t] - tsum + partials[blockIdx.x];
    int4 o;
    o.x = excl;
    o.y = o.x + c.x;
    o.z = o.y + c.y;
    o.w = o.z + c.z;
    if (base + 3 < n) {
        *(int4*)(offsets + base) = o;
        *(int4*)(cursor + base) = o;
    } else {
        if (base     < n) { offsets[base]     = o.x; cursor[base]     = o.x; }
        if (base + 1 < n) { offsets[base + 1] = o.y; cursor[base + 1] = o.y; }
        if (base + 2 < n) { offsets[base + 2] = o.z; cursor[base + 2] = o.z; }
        if (base + 3 < n) { offsets[base + 3] = o.w; cursor[base + 3] = o.w; }
    }
}

__global__ void lg_scan1(const int* __restrict__ counts, int* __restrict__ offsets,
                         int* __restrict__ cursor, int n) {
    const int T = 1024;
    int t = threadIdx.x;
    int chunk = (n + T - 1) / T;
    int start = t * chunk;
    int end = min(start + chunk, n);
    int sum = 0;
    for (int i = start; i < end; ++i) sum += counts[i];
    __shared__ int sdata[T];
    sdata[t] = sum;
    __syncthreads();
    #pragma unroll
    for (int off = 1; off < T; off <<= 1) {
        int v = (t >= off) ? sdata[t - off] : 0;
        __syncthreads();
        sdata[t] += v;
        __syncthreads();
    }
    int offset = sdata[t] - sum;
    for (int i = start; i < end; ++i) {
        int c = counts[i];
        offsets[i] = offset;
        cursor[i] = offset;
        offset += c;
    }
    if (t == T - 1) offsets[n] = sdata[T - 1];
}

__global__ void lg_fill(const int* __restrict__ rows, const int* __restrict__ cols,
                        const float* __restrict__ vals, int* __restrict__ cursor,
                        int2* __restrict__ edges, int nnz) {
    int e = blockIdx.x * blockDim.x + threadIdx.x;
    if (e >= nnz) return;
    int pos = atomicAdd(&cursor[rows[e]], 1);
    edges[pos] = make_int2(cols[e], __float_as_int(vals[e]));
}

// ---------------- pull SpMM v2 ----------------
// One wave per row. float4 per lane: 16 lanes cover D=64; the 4 sub-groups
// process 4 consecutive edges per loop step -> one load instruction fetches
// 4 edges x 256B = 16 cache lines. Unroll x2 -> 32 lines in flight/wave/step.
// Gathers from (c < split ? srcA : srcB) so layer 0 reads user/item directly.
// isFinal: sum = (sum + out) * 0.25, no nxt write.
__global__ void lg_pull(const int* __restrict__ offs, const int2* __restrict__ edges,
                        const float* __restrict__ srcA, const float* __restrict__ srcB,
                        int split, float* __restrict__ nxt, float* __restrict__ sum,
                        int n, int isFinal) {
    int row = blockIdx.x * (blockDim.x >> 6) + (threadIdx.x >> 6);
    if (row >= n) return;
    int lane = threadIdx.x & 63;
    int sub = lane >> 4;    // which of 4 edges in the group
    int q = lane & 15;      // float4 slot: dims [4q, 4q+3]

    int beg = offs[row];
    int end = offs[row + 1];
    float4 acc = make_float4(0.f, 0.f, 0.f, 0.f);

    int j = beg + sub;
    for (; j + 4 < end; j += 8) {
        int2 e0 = edges[j];
        int2 e1 = edges[j + 4];
        const float* p0 = (e0.x < split) ? srcA + (size_t)e0.x * D
                                         : srcB + (size_t)(e0.x - split) * D;
        const float* p1 = (e1.x < split) ? srcA + (size_t)e1.x * D
                                         : srcB + (size_t)(e1.x - split) * D;
        float4 g0 = ((const float4*)p0)[q];
        float4 g1 = ((const float4*)p1)[q];
        float v0 = __int_as_float(e0.y);
        float v1 = __int_as_float(e1.y);
        acc.x += v0 * g0.x + v1 * g1.x;
        acc.y += v0 * g0.y + v1 * g1.y;
        acc.z += v0 * g0.z + v1 * g1.z;
        acc.w += v0 * g0.w + v1 * g1.w;
    }
    for (; j < end; j += 4) {
        int2 e = edges[j];
        const float* p = (e.x < split) ? srcA + (size_t)e.x * D
                                       : srcB + (size_t)(e.x - split) * D;
        float4 g = ((const float4*)p)[q];
        float v = __int_as_float(e.y);
        acc.x += v * g.x;
        acc.y += v * g.y;
        acc.z += v * g.z;
        acc.w += v * g.w;
    }

    // reduce the 4 sub-group partials (lanes q, q+16, q+32, q+48)
    acc.x += __shfl_xor(acc.x, 16, 64); acc.x += __shfl_xor(acc.x, 32, 64);
    acc.y += __shfl_xor(acc.y, 16, 64); acc.y += __shfl_xor(acc.y, 32, 64);
    acc.z += __shfl_xor(acc.z, 16, 64); acc.z += __shfl_xor(acc.z, 32, 64);
    acc.w += __shfl_xor(acc.w, 16, 64); acc.w += __shfl_xor(acc.w, 32, 64);

    // L2 norm over the 16 q-lanes (all sub-groups now identical)
    float ss = acc.x * acc.x + acc.y * acc.y + acc.z * acc.z + acc.w * acc.w;
    #pragma unroll
    for (int off = 1; off < 16; off <<= 1) ss += __shfl_xor(ss, off, 64);
    float inv = 1.0f / fmaxf(sqrtf(ss), 1e-12f);
    float4 o = make_float4(acc.x * inv, acc.y * inv, acc.z * inv, acc.w * inv);

    size_t base = (size_t)row * D;
    if (!isFinal) {
        if (sub == 0) ((float4*)(nxt + base))[q] = o;
        if (sub == 1) {
            float4 s = ((const float4*)(sum + base))[q];
            s.x += o.x; s.y += o.y; s.z += o.z; s.w += o.w;
            ((float4*)(sum + base))[q] = s;
        }
    } else {
        if (sub == 0) {
            float4 s = ((const float4*)(sum + base))[q];
            s.x = (s.x + o.x) * 0.25f;
            s.y = (s.y + o.y) * 0.25f;
            s.z = (s.z + o.z) * 0.25f;
            s.w = (s.w + o.w) * 0.25f;
            ((float4*)(sum + base))[q] = s;
        }
    }
}

// ---------------- fallback (atomic-scatter path) ----------------

__global__ void lg_scatter(const int* __restrict__ rows, const int* __restrict__ cols,
                           const float* __restrict__ vals,
                           const float* __restrict__ cur, float* __restrict__ next,
                           int nnz) {
    int gid = blockIdx.x * blockDim.x + threadIdx.x;
    int e = gid >> 6;
    int d = gid & 63;
    if (e >= nnz) return;
    atomicAdd(&next[rows[e] * D + d], vals[e] * cur[cols[e] * D + d]);
}

__global__ void lg_norm_acc(float* __restrict__ emb, float* __restrict__ sum, int n) {
    int row = blockIdx.x * (blockDim.x >> 6) + (threadIdx.x >> 6);
    int d = threadIdx.x & 63;
    if (row >= n) return;
    int idx = row * D + d;
    float v = emb[idx];
    float ss = v * v;
    #pragma unroll
    for (int off = 32; off > 0; off >>= 1) ss += __shfl_xor(ss, off, 64);
    float out = v / fmaxf(sqrtf(ss), 1e-12f);
    emb[idx] = out;
    sum[idx] += out;
}

// ---------------- launch ----------------

extern "C" void kernel_launch(void* const* d_in, const int* in_sizes, int n_in,
                              void* d_out, int out_size, void* d_ws, size_t ws_size,
                              hipStream_t stream) {
    const float* user = (const float*)d_in[0];
    const float* item = (const float*)d_in[1];
    const float* vals = (const float*)d_in[2];
    const int*   rows = (const int*)d_in[3];
    const int*   cols = (const int*)d_in[4];

    const int nU  = in_sizes[0] / D;
    const int nI  = in_sizes[1] / D;
    const int N   = nU + nI;
    const int nnz = in_sizes[2];

    const size_t embElems = (size_t)N * D;
    float* sum = (float*)d_out;
    const int total4 = (int)(embElems / 4);

    char* p = (char*)d_ws;
    float* buf0 = (float*)p;      p = align16(p + embElems * sizeof(float));
    float* buf1 = (float*)p;      p = align16(p + embElems * sizeof(float));
    int* counts   = (int*)p;      p = align16(p + (size_t)N * sizeof(int));
    int* offsets  = (int*)p;      p = align16(p + (size_t)(N + 1) * sizeof(int));
    int* cursor   = (int*)p;      p = align16(p + (size_t)N * sizeof(int));
    int* partials = (int*)p;      p = align16(p + 256 * sizeof(int));
    int2* edges   = (int2*)p;     p = align16(p + (size_t)nnz * sizeof(int2));
    size_t csrBytes = (size_t)(p - (char*)d_ws);

    if (ws_size >= csrBytes) {
        lg_init_sum<<<(total4 + 255) / 256, 256, 0, stream>>>(
            (const float4*)user, (const float4*)item, (float4*)sum, nU * D / 4, total4);

        // ---- CSR build ----
        hipMemsetAsync(counts, 0, (size_t)N * sizeof(int), stream);
        int eb = (nnz + 255) / 256;
        lg_hist<<<eb, 256, 0, stream>>>(rows, counts, nnz);

        int nb = (N + SCAN_CHUNK - 1) / SCAN_CHUNK;
        if (nb <= 256) {
            lg_scan_reduce<<<nb, 256, 0, stream>>>(counts, partials, N);
            lg_scan_partials<<<1, 256, 0, stream>>>(partials, nb, offsets + N);
            lg_scan_final<<<nb, 256, 0, stream>>>(counts, partials, offsets, cursor, N);
        } else {
            lg_scan1<<<1, 1024, 0, stream>>>(counts, offsets, cursor, N);
        }
        lg_fill<<<eb, 256, 0, stream>>>(rows, cols, vals, cursor, edges, nnz);

        // ---- 3 layers, fused normalize/accumulate; last layer fuses the mean ----
        int rb = (N + 3) / 4;
        // layer 0: gather straight from user/item
        lg_pull<<<rb, 256, 0, stream>>>(offsets, edges, user, item, nU, buf0, sum, N, 0);
        // layer 1
        lg_pull<<<rb, 256, 0, stream>>>(offsets, edges, buf0, buf0, 0, buf1, sum, N, 0);
        // layer 2 (final): sum = (sum + out) * 0.25
        lg_pull<<<rb, 256, 0, stream>>>(offsets, edges, buf1, buf1, 0, buf0, sum, N, 1);
    } else {
        lg_init<<<(total4 + 255) / 256, 256, 0, stream>>>(
            (const float4*)user, (const float4*)item,
            (float4*)buf0, (float4*)sum, nU * D / 4, total4);
        float* cur = buf0;
        float* nxt = buf1;
        for (int layer = 0; layer < 3; ++layer) {
            hipMemsetAsync(nxt, 0, embElems * sizeof(float), stream);
            int totThreads = nnz * 64;
            int blocks = (totThreads + 255) / 256;
            lg_scatter<<<blocks, 256, 0, stream>>>(rows, cols, vals, cur, nxt, nnz);
            lg_norm_acc<<<(N + 3) / 4, 256, 0, stream>>>(nxt, sum, N);
            float* t = cur; cur = nxt; nxt = t;
        }
        lg_final<<<(total4 + 255) / 256, 256, 0, stream>>>((float4*)sum, total4);
    }
}

// Round 5
// 640.100 us; speedup vs baseline: 2.7741x; 1.0782x over previous
//
#include <hip/hip_runtime.h>

#define D 64
#define SCAN_CHUNK 1024

typedef unsigned int u32;
typedef unsigned long long u64;

static inline char* align16(char* p) {
    return (char*)(((uintptr_t)p + 15) & ~(uintptr_t)15);
}

// bf16x2 helpers (packed pair in one u32; low ushort = even element)
__device__ __forceinline__ float bflo(u32 p) { return __uint_as_float(p << 16); }
__device__ __forceinline__ float bfhi(u32 p) { return __uint_as_float(p & 0xFFFF0000u); }
__device__ __forceinline__ u32 pack_bf16x2(float a, float b) {
    u32 ua = __float_as_uint(a);
    u32 ub = __float_as_uint(b);
    ua = (ua + 0x7FFFu + ((ua >> 16) & 1u)) >> 16;   // RNE
    ub = (ub + 0x7FFFu + ((ub >> 16) & 1u)) >> 16;
    return ua | (ub << 16);
}

// ---------------- init / epilogue ----------------

// t0 = bf16(concat(user, item)); each thread handles one float4 -> one uint2
__global__ void lg_to_bf16(const float4* __restrict__ user, const float4* __restrict__ item,
                           uint2* __restrict__ dst, int user_vec4, int total_vec4) {
    int i = blockIdx.x * blockDim.x + threadIdx.x;
    if (i >= total_vec4) return;
    float4 v = (i < user_vec4) ? user[i] : item[i - user_vec4];
    dst[i] = make_uint2(pack_bf16x2(v.x, v.y), pack_bf16x2(v.z, v.w));
}

// out = (e0_fp32 + e1 + e2 + e3) / 4  (e0 straight from user/item, exact)
__global__ void lg_mean(const float4* __restrict__ user, const float4* __restrict__ item,
                        int user_vec4,
                        const uint2* __restrict__ e1, const uint2* __restrict__ e2,
                        const uint2* __restrict__ e3,
                        float4* __restrict__ out, int total_vec4) {
    int i = blockIdx.x * blockDim.x + threadIdx.x;
    if (i >= total_vec4) return;
    float4 a = (i < user_vec4) ? user[i] : item[i - user_vec4];
    uint2 b = e1[i], c = e2[i], d = e3[i];
    float4 r;
    r.x = (a.x + bflo(b.x) + bflo(c.x) + bflo(d.x)) * 0.25f;
    r.y = (a.y + bfhi(b.x) + bfhi(c.x) + bfhi(d.x)) * 0.25f;
    r.z = (a.z + bflo(b.y) + bflo(c.y) + bflo(d.y)) * 0.25f;
    r.w = (a.w + bfhi(b.y) + bfhi(c.y) + bfhi(d.y)) * 0.25f;
    out[i] = r;
}

// ---------------- CSR build ----------------

__global__ void lg_hist(const int* __restrict__ rows, int* __restrict__ counts, int nnz) {
    int e = blockIdx.x * blockDim.x + threadIdx.x;
    if (e >= nnz) return;
    atomicAdd(&counts[rows[e]], 1);
}

__global__ void lg_scan_reduce(const int* __restrict__ counts, int* __restrict__ partials, int n) {
    __shared__ int s[4];
    int base = blockIdx.x * SCAN_CHUNK;
    int sum = 0;
    for (int i = threadIdx.x; i < SCAN_CHUNK; i += 256) {
        int idx = base + i;
        if (idx < n) sum += counts[idx];
    }
    #pragma unroll
    for (int off = 32; off > 0; off >>= 1) sum += __shfl_xor(sum, off, 64);
    if ((threadIdx.x & 63) == 0) s[threadIdx.x >> 6] = sum;
    __syncthreads();
    if (threadIdx.x == 0) partials[blockIdx.x] = s[0] + s[1] + s[2] + s[3];
}

__global__ void lg_scan_partials(int* __restrict__ partials, int nb, int* __restrict__ offsets_end) {
    __shared__ int s[256];
    int t = threadIdx.x;
    int v = (t < nb) ? partials[t] : 0;
    s[t] = v;
    __syncthreads();
    #pragma unroll
    for (int off = 1; off < 256; off <<= 1) {
        int x = (t >= off) ? s[t - off] : 0;
        __syncthreads();
        s[t] += x;
        __syncthreads();
    }
    if (t < nb) partials[t] = s[t] - v;
    if (t == 255) *offsets_end = s[255];
}

__global__ void lg_scan_final(const int* __restrict__ counts, const int* __restrict__ partials,
                              int* __restrict__ offsets, int* __restrict__ cursor, int n) {
    __shared__ int s[256];
    int t = threadIdx.x;
    int base = blockIdx.x * SCAN_CHUNK + t * 4;
    int4 c = make_int4(0, 0, 0, 0);
    if (base + 3 < n) {
        c = *(const int4*)(counts + base);
    } else {
        if (base     < n) c.x = counts[base];
        if (base + 1 < n) c.y = counts[base + 1];
        if (base + 2 < n) c.z = counts[base + 2];
        if (base + 3 < n) c.w = counts[base + 3];
    }
    int tsum = c.x + c.y + c.z + c.w;
    s[t] = tsum;
    __syncthreads();
    #pragma unroll
    for (int off = 1; off < 256; off <<= 1) {
        int x = (t >= off) ? s[t - off] : 0;
        __syncthreads();
        s[t] += x;
        __syncthreads();
    }
    int excl = s[t] - tsum + partials[blockIdx.x];
    int4 o;
    o.x = excl;
    o.y = o.x + c.x;
    o.z = o.y + c.y;
    o.w = o.z + c.z;
    if (base + 3 < n) {
        *(int4*)(offsets + base) = o;
        *(int4*)(cursor + base) = o;
    } else {
        if (base     < n) { offsets[base]     = o.x; cursor[base]     = o.x; }
        if (base + 1 < n) { offsets[base + 1] = o.y; cursor[base + 1] = o.y; }
        if (base + 2 < n) { offsets[base + 2] = o.z; cursor[base + 2] = o.z; }
        if (base + 3 < n) { offsets[base + 3] = o.w; cursor[base + 3] = o.w; }
    }
}

__global__ void lg_scan1(const int* __restrict__ counts, int* __restrict__ offsets,
                         int* __restrict__ cursor, int n) {
    const int T = 1024;
    int t = threadIdx.x;
    int chunk = (n + T - 1) / T;
    int start = t * chunk;
    int end = min(start + chunk, n);
    int sum = 0;
    for (int i = start; i < end; ++i) sum += counts[i];
    __shared__ int sdata[T];
    sdata[t] = sum;
    __syncthreads();
    #pragma unroll
    for (int off = 1; off < T; off <<= 1) {
        int v = (t >= off) ? sdata[t - off] : 0;
        __syncthreads();
        sdata[t] += v;
        __syncthreads();
    }
    int offset = sdata[t] - sum;
    for (int i = start; i < end; ++i) {
        int c = counts[i];
        offsets[i] = offset;
        cursor[i] = offset;
        offset += c;
    }
    if (t == T - 1) offsets[n] = sdata[T - 1];
}

// edges[pos] = {col, val_bits} as one nontemporal 8B store
__global__ void lg_fill(const int* __restrict__ rows, const int* __restrict__ cols,
                        const float* __restrict__ vals, int* __restrict__ cursor,
                        u64* __restrict__ edges, int nnz) {
    int e = blockIdx.x * blockDim.x + threadIdx.x;
    if (e >= nnz) return;
    int pos = atomicAdd(&cursor[rows[e]], 1);
    u64 packed = (u64)(u32)cols[e] | ((u64)__float_as_uint(vals[e]) << 32);
    __builtin_nontemporal_store(packed, &edges[pos]);
}

// ---------------- pull SpMM (bf16 gather, fp32 accumulate) ----------------
// One wave per row; 16 lanes x uint2 (4 bf16) cover D=64; 4 sub-groups take
// 4 consecutive edges per step; x2 unroll -> 8 edges / 16 lines in flight.
__global__ void lg_pull_bf16(const int* __restrict__ offs, const int2* __restrict__ edges,
                             const u32* __restrict__ src,   // bf16 table, N x 32 u32
                             u32* __restrict__ nxt, int n) {
    int row = blockIdx.x * (blockDim.x >> 6) + (threadIdx.x >> 6);
    if (row >= n) return;
    int lane = threadIdx.x & 63;
    int sub = lane >> 4;
    int q = lane & 15;   // owns dims [4q, 4q+3] = uint2 slot q

    int beg = offs[row];
    int end = offs[row + 1];
    float4 acc = make_float4(0.f, 0.f, 0.f, 0.f);

    int j = beg + sub;
    for (; j + 4 < end; j += 8) {
        int2 e0 = edges[j];
        int2 e1 = edges[j + 4];
        uint2 g0 = ((const uint2*)(src + (size_t)e0.x * 32))[q];
        uint2 g1 = ((const uint2*)(src + (size_t)e1.x * 32))[q];
        float v0 = __int_as_float(e0.y);
        float v1 = __int_as_float(e1.y);
        acc.x += v0 * bflo(g0.x) + v1 * bflo(g1.x);
        acc.y += v0 * bfhi(g0.x) + v1 * bfhi(g1.x);
        acc.z += v0 * bflo(g0.y) + v1 * bflo(g1.y);
        acc.w += v0 * bfhi(g0.y) + v1 * bfhi(g1.y);
    }
    for (; j < end; j += 4) {
        int2 e = edges[j];
        uint2 g = ((const uint2*)(src + (size_t)e.x * 32))[q];
        float v = __int_as_float(e.y);
        acc.x += v * bflo(g.x);
        acc.y += v * bfhi(g.x);
        acc.z += v * bflo(g.y);
        acc.w += v * bfhi(g.y);
    }

    // reduce 4 sub-group partials (lanes q, q+16, q+32, q+48)
    acc.x += __shfl_xor(acc.x, 16, 64); acc.x += __shfl_xor(acc.x, 32, 64);
    acc.y += __shfl_xor(acc.y, 16, 64); acc.y += __shfl_xor(acc.y, 32, 64);
    acc.z += __shfl_xor(acc.z, 16, 64); acc.z += __shfl_xor(acc.z, 32, 64);
    acc.w += __shfl_xor(acc.w, 16, 64); acc.w += __shfl_xor(acc.w, 32, 64);

    // L2 norm across the 16 q-lanes (sub-groups identical now)
    float ss = acc.x * acc.x + acc.y * acc.y + acc.z * acc.z + acc.w * acc.w;
    #pragma unroll
    for (int off = 1; off < 16; off <<= 1) ss += __shfl_xor(ss, off, 64);
    float inv = 1.0f / fmaxf(sqrtf(ss), 1e-12f);

    if (sub == 0) {
        uint2 o = make_uint2(pack_bf16x2(acc.x * inv, acc.y * inv),
                             pack_bf16x2(acc.z * inv, acc.w * inv));
        ((uint2*)(nxt + (size_t)row * 32))[q] = o;
    }
}

// ---------------- fallback (atomic-scatter fp32 path) ----------------

__global__ void lg_init(const float4* __restrict__ user, const float4* __restrict__ item,
                        float4* __restrict__ cur, float4* __restrict__ sum,
                        int user_vec4, int total_vec4) {
    int i = blockIdx.x * blockDim.x + threadIdx.x;
    if (i >= total_vec4) return;
    float4 v = (i < user_vec4) ? user[i] : item[i - user_vec4];
    cur[i] = v;
    sum[i] = v;
}

__global__ void lg_scatter(const int* __restrict__ rows, const int* __restrict__ cols,
                           const float* __restrict__ vals,
                           const float* __restrict__ cur, float* __restrict__ next,
                           int nnz) {
    int gid = blockIdx.x * blockDim.x + threadIdx.x;
    int e = gid >> 6;
    int d = gid & 63;
    if (e >= nnz) return;
    atomicAdd(&next[rows[e] * D + d], vals[e] * cur[cols[e] * D + d]);
}

__global__ void lg_norm_acc(float* __restrict__ emb, float* __restrict__ sum, int n) {
    int row = blockIdx.x * (blockDim.x >> 6) + (threadIdx.x >> 6);
    int d = threadIdx.x & 63;
    if (row >= n) return;
    int idx = row * D + d;
    float v = emb[idx];
    float ss = v * v;
    #pragma unroll
    for (int off = 32; off > 0; off >>= 1) ss += __shfl_xor(ss, off, 64);
    float out = v / fmaxf(sqrtf(ss), 1e-12f);
    emb[idx] = out;
    sum[idx] += out;
}

__global__ void lg_final(float4* __restrict__ out, int n4) {
    int i = blockIdx.x * blockDim.x + threadIdx.x;
    if (i >= n4) return;
    float4 s = out[i];
    out[i] = make_float4(s.x * 0.25f, s.y * 0.25f, s.z * 0.25f, s.w * 0.25f);
}

// ---------------- launch ----------------

extern "C" void kernel_launch(void* const* d_in, const int* in_sizes, int n_in,
                              void* d_out, int out_size, void* d_ws, size_t ws_size,
                              hipStream_t stream) {
    const float* user = (const float*)d_in[0];
    const float* item = (const float*)d_in[1];
    const float* vals = (const float*)d_in[2];
    const int*   rows = (const int*)d_in[3];
    const int*   cols = (const int*)d_in[4];

    const int nU  = in_sizes[0] / D;
    const int nI  = in_sizes[1] / D;
    const int N   = nU + nI;
    const int nnz = in_sizes[2];

    const size_t embElems = (size_t)N * D;
    const size_t embU32   = (size_t)N * 32;       // bf16 table in u32 units
    const int total4 = (int)(embElems / 4);
    float* out = (float*)d_out;

    // ws layout (bf16 path)
    char* p = (char*)d_ws;
    u32* t0  = (u32*)p;           p = align16(p + embU32 * sizeof(u32));
    u32* e1b = (u32*)p;           p = align16(p + embU32 * sizeof(u32));
    u32* e2b = (u32*)p;           p = align16(p + embU32 * sizeof(u32));
    u32* e3b = (u32*)p;           p = align16(p + embU32 * sizeof(u32));
    int* counts   = (int*)p;      p = align16(p + (size_t)N * sizeof(int));
    int* offsets  = (int*)p;      p = align16(p + (size_t)(N + 1) * sizeof(int));
    int* cursor   = (int*)p;      p = align16(p + (size_t)N * sizeof(int));
    int* partials = (int*)p;      p = align16(p + 256 * sizeof(int));
    u64* edges    = (u64*)p;      p = align16(p + (size_t)nnz * sizeof(u64));
    size_t needBytes = (size_t)(p - (char*)d_ws);

    if (ws_size >= needBytes) {
        // bf16 copy of layer-0 table
        lg_to_bf16<<<(total4 + 255) / 256, 256, 0, stream>>>(
            (const float4*)user, (const float4*)item, (uint2*)t0, nU * D / 4, total4);

        // ---- CSR build ----
        hipMemsetAsync(counts, 0, (size_t)N * sizeof(int), stream);
        int eb = (nnz + 255) / 256;
        lg_hist<<<eb, 256, 0, stream>>>(rows, counts, nnz);

        int nb = (N + SCAN_CHUNK - 1) / SCAN_CHUNK;
        if (nb <= 256) {
            lg_scan_reduce<<<nb, 256, 0, stream>>>(counts, partials, N);
            lg_scan_partials<<<1, 256, 0, stream>>>(partials, nb, offsets + N);
            lg_scan_final<<<nb, 256, 0, stream>>>(counts, partials, offsets, cursor, N);
        } else {
            lg_scan1<<<1, 1024, 0, stream>>>(counts, offsets, cursor, N);
        }
        lg_fill<<<eb, 256, 0, stream>>>(rows, cols, vals, cursor, edges, nnz);

        // ---- 3 bf16 pulls ----
        int rb = (N + 3) / 4;
        lg_pull_bf16<<<rb, 256, 0, stream>>>(offsets, (const int2*)edges, t0,  e1b, N);
        lg_pull_bf16<<<rb, 256, 0, stream>>>(offsets, (const int2*)edges, e1b, e2b, N);
        lg_pull_bf16<<<rb, 256, 0, stream>>>(offsets, (const int2*)edges, e2b, e3b, N);

        // ---- epilogue: mean of {fp32 layer0, bf16 e1..e3} ----
        lg_mean<<<(total4 + 255) / 256, 256, 0, stream>>>(
            (const float4*)user, (const float4*)item, nU * D / 4,
            (const uint2*)e1b, (const uint2*)e2b, (const uint2*)e3b,
            (float4*)out, total4);
    } else {
        // fallback: fp32 atomic scatter (2 fp32 buffers fit in t0..e3 region)
        float* buf0 = (float*)t0;
        float* buf1 = buf0 + embElems;
        float* sum  = out;
        lg_init<<<(total4 + 255) / 256, 256, 0, stream>>>(
            (const float4*)user, (const float4*)item,
            (float4*)buf0, (float4*)sum, nU * D / 4, total4);
        float* cur = buf0;
        float* nxt = buf1;
        for (int layer = 0; layer < 3; ++layer) {
            hipMemsetAsync(nxt, 0, embElems * sizeof(float), stream);
            int totThreads = nnz * 64;
            int blocks = (totThreads + 255) / 256;
            lg_scatter<<<blocks, 256, 0, stream>>>(rows, cols, vals, cur, nxt, nnz);
            lg_norm_acc<<<(N + 3) / 4, 256, 0, stream>>>(nxt, sum, N);
            float* t = cur; cur = nxt; nxt = t;
        }
        lg_final<<<(total4 + 255) / 256, 256, 0, stream>>>((float4*)sum, total4);
    }
}

// Round 6
// 587.141 us; speedup vs baseline: 3.0243x; 1.0902x over previous
//
#include <hip/hip_runtime.h>

#define D 64
#define SCAN_CHUNK 1024
#define BUCKET_SHIFT 8
#define ROWS_PER_BUCKET 256
#define NBUCK_MAX 1024
#define BINA_CHUNK 16384

typedef unsigned int u32;
typedef unsigned long long u64;

static inline char* align16(char* p) {
    return (char*)(((uintptr_t)p + 15) & ~(uintptr_t)15);
}

// bf16x2 helpers (packed pair in one u32; low ushort = even element)
__device__ __forceinline__ float bflo(u32 p) { return __uint_as_float(p << 16); }
__device__ __forceinline__ float bfhi(u32 p) { return __uint_as_float(p & 0xFFFF0000u); }
__device__ __forceinline__ u32 pack_bf16x2(float a, float b) {
    u32 ua = __float_as_uint(a);
    u32 ub = __float_as_uint(b);
    ua = (ua + 0x7FFFu + ((ua >> 16) & 1u)) >> 16;   // RNE
    ub = (ub + 0x7FFFu + ((ub >> 16) & 1u)) >> 16;
    return ua | (ub << 16);
}

// ---------------- init / epilogue ----------------

__global__ void lg_to_bf16(const float4* __restrict__ user, const float4* __restrict__ item,
                           uint2* __restrict__ dst, int user_vec4, int total_vec4) {
    int i = blockIdx.x * blockDim.x + threadIdx.x;
    if (i >= total_vec4) return;
    float4 v = (i < user_vec4) ? user[i] : item[i - user_vec4];
    dst[i] = make_uint2(pack_bf16x2(v.x, v.y), pack_bf16x2(v.z, v.w));
}

__global__ void lg_mean(const float4* __restrict__ user, const float4* __restrict__ item,
                        int user_vec4,
                        const uint2* __restrict__ e1, const uint2* __restrict__ e2,
                        const uint2* __restrict__ e3,
                        float4* __restrict__ out, int total_vec4) {
    int i = blockIdx.x * blockDim.x + threadIdx.x;
    if (i >= total_vec4) return;
    float4 a = (i < user_vec4) ? user[i] : item[i - user_vec4];
    uint2 b = e1[i], c = e2[i], d = e3[i];
    float4 r;
    r.x = (a.x + bflo(b.x) + bflo(c.x) + bflo(d.x)) * 0.25f;
    r.y = (a.y + bfhi(b.x) + bfhi(c.x) + bfhi(d.x)) * 0.25f;
    r.z = (a.z + bflo(b.y) + bflo(c.y) + bflo(d.y)) * 0.25f;
    r.w = (a.w + bfhi(b.y) + bfhi(c.y) + bfhi(d.y)) * 0.25f;
    out[i] = r;
}

// ---------------- CSR build: hist + scan ----------------

__global__ void lg_hist(const int* __restrict__ rows, int* __restrict__ counts, int nnz) {
    int e = blockIdx.x * blockDim.x + threadIdx.x;
    if (e >= nnz) return;
    atomicAdd(&counts[rows[e]], 1);
}

__global__ void lg_scan_reduce(const int* __restrict__ counts, int* __restrict__ partials, int n) {
    __shared__ int s[4];
    int base = blockIdx.x * SCAN_CHUNK;
    int sum = 0;
    for (int i = threadIdx.x; i < SCAN_CHUNK; i += 256) {
        int idx = base + i;
        if (idx < n) sum += counts[idx];
    }
    #pragma unroll
    for (int off = 32; off > 0; off >>= 1) sum += __shfl_xor(sum, off, 64);
    if ((threadIdx.x & 63) == 0) s[threadIdx.x >> 6] = sum;
    __syncthreads();
    if (threadIdx.x == 0) partials[blockIdx.x] = s[0] + s[1] + s[2] + s[3];
}

__global__ void lg_scan_partials(int* __restrict__ partials, int nb, int* __restrict__ offsets_end) {
    __shared__ int s[256];
    int t = threadIdx.x;
    int v = (t < nb) ? partials[t] : 0;
    s[t] = v;
    __syncthreads();
    #pragma unroll
    for (int off = 1; off < 256; off <<= 1) {
        int x = (t >= off) ? s[t - off] : 0;
        __syncthreads();
        s[t] += x;
        __syncthreads();
    }
    if (t < nb) partials[t] = s[t] - v;
    if (t == 255) *offsets_end = s[255];
}

__global__ void lg_scan_final(const int* __restrict__ counts, const int* __restrict__ partials,
                              int* __restrict__ offsets, int n) {
    __shared__ int s[256];
    int t = threadIdx.x;
    int base = blockIdx.x * SCAN_CHUNK + t * 4;
    int4 c = make_int4(0, 0, 0, 0);
    if (base + 3 < n) {
        c = *(const int4*)(counts + base);
    } else {
        if (base     < n) c.x = counts[base];
        if (base + 1 < n) c.y = counts[base + 1];
        if (base + 2 < n) c.z = counts[base + 2];
        if (base + 3 < n) c.w = counts[base + 3];
    }
    int tsum = c.x + c.y + c.z + c.w;
    s[t] = tsum;
    __syncthreads();
    #pragma unroll
    for (int off = 1; off < 256; off <<= 1) {
        int x = (t >= off) ? s[t - off] : 0;
        __syncthreads();
        s[t] += x;
        __syncthreads();
    }
    int excl = s[t] - tsum + partials[blockIdx.x];
    int4 o;
    o.x = excl;
    o.y = o.x + c.x;
    o.z = o.y + c.y;
    o.w = o.z + c.z;
    if (base + 3 < n) {
        *(int4*)(offsets + base) = o;
    } else {
        if (base     < n) offsets[base]     = o.x;
        if (base + 1 < n) offsets[base + 1] = o.y;
        if (base + 2 < n) offsets[base + 2] = o.z;
        if (base + 3 < n) offsets[base + 3] = o.w;
    }
}

__global__ void lg_scan1(const int* __restrict__ counts, int* __restrict__ offsets, int n) {
    const int T = 1024;
    int t = threadIdx.x;
    int chunk = (n + T - 1) / T;
    int start = t * chunk;
    int end = min(start + chunk, n);
    int sum = 0;
    for (int i = start; i < end; ++i) sum += counts[i];
    __shared__ int sdata[T];
    sdata[t] = sum;
    __syncthreads();
    #pragma unroll
    for (int off = 1; off < T; off <<= 1) {
        int v = (t >= off) ? sdata[t - off] : 0;
        __syncthreads();
        sdata[t] += v;
        __syncthreads();
    }
    int offset = sdata[t] - sum;
    for (int i = start; i < end; ++i) {
        int c = counts[i];
        offsets[i] = offset;
        offset += c;
    }
    if (t == T - 1) offsets[n] = sdata[T - 1];
}

// ---------------- two-level bucket sort (replaces atomic scatter fill) ----------------

// bucketCursor[b] = offsets[b << BUCKET_SHIFT]
__global__ void lg_bucket_init(const int* __restrict__ offsets, int* __restrict__ bucketCursor,
                               int nbuck) {
    int b = blockIdx.x * blockDim.x + threadIdx.x;
    if (b >= nbuck) return;
    bucketCursor[b] = offsets[b << BUCKET_SHIFT];
}

// Pass A: coarse scatter into tmp, packed {localrow:8|col:24, val}.
// Per-block LDS histogram -> one global atomic per touched bucket -> scatter
// in ~contiguous per-bucket runs.
__global__ void lg_binA(const int* __restrict__ rows, const int* __restrict__ cols,
                        const float* __restrict__ vals, int* __restrict__ bucketCursor,
                        u64* __restrict__ tmp, int nnz, int nbuck) {
    __shared__ int hist[NBUCK_MAX];
    __shared__ int base[NBUCK_MAX];
    int tid = threadIdx.x;
    int bstart = blockIdx.x * BINA_CHUNK;
    int bend = min(bstart + BINA_CHUNK, nnz);

    for (int i = tid; i < nbuck; i += 256) hist[i] = 0;
    __syncthreads();
    for (int e = bstart + tid; e < bend; e += 256)
        atomicAdd(&hist[rows[e] >> BUCKET_SHIFT], 1);
    __syncthreads();
    for (int b = tid; b < nbuck; b += 256) {
        int c = hist[b];
        base[b] = (c > 0) ? atomicAdd(&bucketCursor[b], c) : 0;
        hist[b] = 0;   // reuse as local cursor
    }
    __syncthreads();
    for (int e = bstart + tid; e < bend; e += 256) {
        int r = rows[e];
        int b = r >> BUCKET_SHIFT;
        int pos = base[b] + atomicAdd(&hist[b], 1);
        u32 key = ((u32)(r & (ROWS_PER_BUCKET - 1)) << 24) | (u32)cols[e];
        u64 packed = (u64)key | ((u64)__float_as_uint(vals[e]) << 32);
        __builtin_nontemporal_store(packed, &tmp[pos]);
    }
}

// Pass B: one block per bucket; writes land in the bucket's contiguous CSR
// range (single CU -> single XCD L2 -> full-line writebacks).
__global__ void lg_binB(const int* __restrict__ offsets, const u64* __restrict__ tmp,
                        int2* __restrict__ edges, int n, int nbuck) {
    __shared__ int cursor[ROWS_PER_BUCKET];
    int bucket = blockIdx.x;
    int row0 = bucket << BUCKET_SHIFT;
    int tid = threadIdx.x;
    int r = row0 + tid;
    cursor[tid] = (r < n) ? offsets[r] : 0;
    __syncthreads();
    int bstart = offsets[row0];
    int bend = offsets[min(row0 + ROWS_PER_BUCKET, n)];
    for (int e = bstart + tid; e < bend; e += 256) {
        u64 p = tmp[e];
        u32 key = (u32)p;
        int lr = key >> 24;
        int col = (int)(key & 0xFFFFFFu);
        int pos = atomicAdd(&cursor[lr], 1);
        edges[pos] = make_int2(col, (int)(u32)(p >> 32));
    }
}

// Fallback fill (atomic scatter) if nbuck > NBUCK_MAX or ws too small.
__global__ void lg_fill(const int* __restrict__ rows, const int* __restrict__ cols,
                        const float* __restrict__ vals, int* __restrict__ cursor,
                        u64* __restrict__ edges, int nnz) {
    int e = blockIdx.x * blockDim.x + threadIdx.x;
    if (e >= nnz) return;
    int pos = atomicAdd(&cursor[rows[e]], 1);
    u64 packed = (u64)(u32)cols[e] | ((u64)__float_as_uint(vals[e]) << 32);
    __builtin_nontemporal_store(packed, &edges[pos]);
}

__global__ void lg_cursor_copy(const int* __restrict__ offsets, int* __restrict__ cursor, int n) {
    int i = blockIdx.x * blockDim.x + threadIdx.x;
    if (i < n) cursor[i] = offsets[i];
}

// ---------------- pull SpMM (bf16 gather, fp32 accumulate) ----------------

__global__ void lg_pull_bf16(const int* __restrict__ offs, const int2* __restrict__ edges,
                             const u32* __restrict__ src,   // bf16 table, N x 32 u32
                             u32* __restrict__ nxt, int n) {
    int row = blockIdx.x * (blockDim.x >> 6) + (threadIdx.x >> 6);
    if (row >= n) return;
    int lane = threadIdx.x & 63;
    int sub = lane >> 4;
    int q = lane & 15;

    int beg = offs[row];
    int end = offs[row + 1];
    float4 acc = make_float4(0.f, 0.f, 0.f, 0.f);

    int j = beg + sub;
    for (; j + 4 < end; j += 8) {
        int2 e0 = edges[j];
        int2 e1 = edges[j + 4];
        uint2 g0 = ((const uint2*)(src + (size_t)e0.x * 32))[q];
        uint2 g1 = ((const uint2*)(src + (size_t)e1.x * 32))[q];
        float v0 = __int_as_float(e0.y);
        float v1 = __int_as_float(e1.y);
        acc.x += v0 * bflo(g0.x) + v1 * bflo(g1.x);
        acc.y += v0 * bfhi(g0.x) + v1 * bfhi(g1.x);
        acc.z += v0 * bflo(g0.y) + v1 * bflo(g1.y);
        acc.w += v0 * bfhi(g0.y) + v1 * bfhi(g1.y);
    }
    for (; j < end; j += 4) {
        int2 e = edges[j];
        uint2 g = ((const uint2*)(src + (size_t)e.x * 32))[q];
        float v = __int_as_float(e.y);
        acc.x += v * bflo(g.x);
        acc.y += v * bfhi(g.x);
        acc.z += v * bflo(g.y);
        acc.w += v * bfhi(g.y);
    }

    acc.x += __shfl_xor(acc.x, 16, 64); acc.x += __shfl_xor(acc.x, 32, 64);
    acc.y += __shfl_xor(acc.y, 16, 64); acc.y += __shfl_xor(acc.y, 32, 64);
    acc.z += __shfl_xor(acc.z, 16, 64); acc.z += __shfl_xor(acc.z, 32, 64);
    acc.w += __shfl_xor(acc.w, 16, 64); acc.w += __shfl_xor(acc.w, 32, 64);

    float ss = acc.x * acc.x + acc.y * acc.y + acc.z * acc.z + acc.w * acc.w;
    #pragma unroll
    for (int off = 1; off < 16; off <<= 1) ss += __shfl_xor(ss, off, 64);
    float inv = 1.0f / fmaxf(sqrtf(ss), 1e-12f);

    if (sub == 0) {
        uint2 o = make_uint2(pack_bf16x2(acc.x * inv, acc.y * inv),
                             pack_bf16x2(acc.z * inv, acc.w * inv));
        ((uint2*)(nxt + (size_t)row * 32))[q] = o;
    }
}

// ---------------- fallback (atomic-scatter fp32 path) ----------------

__global__ void lg_init(const float4* __restrict__ user, const float4* __restrict__ item,
                        float4* __restrict__ cur, float4* __restrict__ sum,
                        int user_vec4, int total_vec4) {
    int i = blockIdx.x * blockDim.x + threadIdx.x;
    if (i >= total_vec4) return;
    float4 v = (i < user_vec4) ? user[i] : item[i - user_vec4];
    cur[i] = v;
    sum[i] = v;
}

__global__ void lg_scatter(const int* __restrict__ rows, const int* __restrict__ cols,
                           const float* __restrict__ vals,
                           const float* __restrict__ cur, float* __restrict__ next,
                           int nnz) {
    int gid = blockIdx.x * blockDim.x + threadIdx.x;
    int e = gid >> 6;
    int d = gid & 63;
    if (e >= nnz) return;
    atomicAdd(&next[rows[e] * D + d], vals[e] * cur[cols[e] * D + d]);
}

__global__ void lg_norm_acc(float* __restrict__ emb, float* __restrict__ sum, int n) {
    int row = blockIdx.x * (blockDim.x >> 6) + (threadIdx.x >> 6);
    int d = threadIdx.x & 63;
    if (row >= n) return;
    int idx = row * D + d;
    float v = emb[idx];
    float ss = v * v;
    #pragma unroll
    for (int off = 32; off > 0; off >>= 1) ss += __shfl_xor(ss, off, 64);
    float out = v / fmaxf(sqrtf(ss), 1e-12f);
    emb[idx] = out;
    sum[idx] += out;
}

__global__ void lg_final(float4* __restrict__ out, int n4) {
    int i = blockIdx.x * blockDim.x + threadIdx.x;
    if (i >= n4) return;
    float4 s = out[i];
    out[i] = make_float4(s.x * 0.25f, s.y * 0.25f, s.z * 0.25f, s.w * 0.25f);
}

// ---------------- launch ----------------

extern "C" void kernel_launch(void* const* d_in, const int* in_sizes, int n_in,
                              void* d_out, int out_size, void* d_ws, size_t ws_size,
                              hipStream_t stream) {
    const float* user = (const float*)d_in[0];
    const float* item = (const float*)d_in[1];
    const float* vals = (const float*)d_in[2];
    const int*   rows = (const int*)d_in[3];
    const int*   cols = (const int*)d_in[4];

    const int nU  = in_sizes[0] / D;
    const int nI  = in_sizes[1] / D;
    const int N   = nU + nI;
    const int nnz = in_sizes[2];

    const size_t embElems = (size_t)N * D;
    const size_t embU32   = (size_t)N * 32;
    const int total4 = (int)(embElems / 4);
    float* out = (float*)d_out;

    // ws layout
    char* p = (char*)d_ws;
    u32* t0  = (u32*)p;           p = align16(p + embU32 * sizeof(u32));
    u32* e1b = (u32*)p;           p = align16(p + embU32 * sizeof(u32));
    u32* e2b = (u32*)p;           p = align16(p + embU32 * sizeof(u32));
    u32* e3b = (u32*)p;           p = align16(p + embU32 * sizeof(u32));
    int* counts   = (int*)p;      p = align16(p + (size_t)N * sizeof(int));
    int* offsets  = (int*)p;      p = align16(p + (size_t)(N + 1) * sizeof(int));
    int* cursor   = (int*)p;      p = align16(p + (size_t)N * sizeof(int));   // fallback fill
    int* partials = (int*)p;      p = align16(p + 256 * sizeof(int));
    int* bucketCursor = (int*)p;  p = align16(p + NBUCK_MAX * sizeof(int));
    u64* edges    = (u64*)p;      p = align16(p + (size_t)nnz * sizeof(u64));
    u64* tmp      = (u64*)p;      p = align16(p + (size_t)nnz * sizeof(u64));
    size_t needBytes = (size_t)(p - (char*)d_ws);
    size_t needNoTmp = needBytes - ((size_t)nnz * sizeof(u64) + 16);

    const int nbuck = (N + ROWS_PER_BUCKET - 1) / ROWS_PER_BUCKET;

    if (ws_size >= needNoTmp) {
        lg_to_bf16<<<(total4 + 255) / 256, 256, 0, stream>>>(
            (const float4*)user, (const float4*)item, (uint2*)t0, nU * D / 4, total4);

        // ---- hist + scan ----
        hipMemsetAsync(counts, 0, (size_t)N * sizeof(int), stream);
        int eb = (nnz + 255) / 256;
        lg_hist<<<eb, 256, 0, stream>>>(rows, counts, nnz);

        int nb = (N + SCAN_CHUNK - 1) / SCAN_CHUNK;
        if (nb <= 256) {
            lg_scan_reduce<<<nb, 256, 0, stream>>>(counts, partials, N);
            lg_scan_partials<<<1, 256, 0, stream>>>(partials, nb, offsets + N);
            lg_scan_final<<<nb, 256, 0, stream>>>(counts, partials, offsets, N);
        } else {
            lg_scan1<<<1, 1024, 0, stream>>>(counts, offsets, N);
        }

        // ---- edge sort ----
        if (nbuck <= NBUCK_MAX && ws_size >= needBytes) {
            lg_bucket_init<<<(nbuck + 255) / 256, 256, 0, stream>>>(offsets, bucketCursor, nbuck);
            int ab = (nnz + BINA_CHUNK - 1) / BINA_CHUNK;
            lg_binA<<<ab, 256, 0, stream>>>(rows, cols, vals, bucketCursor, tmp, nnz, nbuck);
            lg_binB<<<nbuck, 256, 0, stream>>>(offsets, tmp, (int2*)edges, N, nbuck);
        } else {
            lg_cursor_copy<<<(N + 255) / 256, 256, 0, stream>>>(offsets, cursor, N);
            lg_fill<<<eb, 256, 0, stream>>>(rows, cols, vals, cursor, edges, nnz);
        }

        // ---- 3 bf16 pulls ----
        int rb = (N + 3) / 4;
        lg_pull_bf16<<<rb, 256, 0, stream>>>(offsets, (const int2*)edges, t0,  e1b, N);
        lg_pull_bf16<<<rb, 256, 0, stream>>>(offsets, (const int2*)edges, e1b, e2b, N);
        lg_pull_bf16<<<rb, 256, 0, stream>>>(offsets, (const int2*)edges, e2b, e3b, N);

        // ---- epilogue ----
        lg_mean<<<(total4 + 255) / 256, 256, 0, stream>>>(
            (const float4*)user, (const float4*)item, nU * D / 4,
            (const uint2*)e1b, (const uint2*)e2b, (const uint2*)e3b,
            (float4*)out, total4);
    } else {
        // fallback: fp32 atomic scatter
        float* buf0 = (float*)t0;
        float* buf1 = buf0 + embElems;
        float* sum  = out;
        lg_init<<<(total4 + 255) / 256, 256, 0, stream>>>(
            (const float4*)user, (const float4*)item,
            (float4*)buf0, (float4*)sum, nU * D / 4, total4);
        float* cur = buf0;
        float* nxt = buf1;
        for (int layer = 0; layer < 3; ++layer) {
            hipMemsetAsync(nxt, 0, embElems * sizeof(float), stream);
            int totThreads = nnz * 64;
            int blocks = (totThreads + 255) / 256;
            lg_scatter<<<blocks, 256, 0, stream>>>(rows, cols, vals, cur, nxt, nnz);
            lg_norm_acc<<<(N + 3) / 4, 256, 0, stream>>>(nxt, sum, N);
            float* t = cur; cur = nxt; nxt = t;
        }
        lg_final<<<(total4 + 255) / 256, 256, 0, stream>>>((float4*)sum, total4);
    }
}

// Round 7
// 524.904 us; speedup vs baseline: 3.3829x; 1.1186x over previous
//
#include <hip/hip_runtime.h>

#define D 64
#define SCAN_CHUNK 1024
#define BUCKET_SHIFT 8
#define ROWS_PER_BUCKET 256
#define NBUCK_MAX 1024
#define BINA_CHUNK 8192
#define BINA_THREADS 512

typedef unsigned int u32;
typedef unsigned long long u64;

static inline char* align16(char* p) {
    return (char*)(((uintptr_t)p + 15) & ~(uintptr_t)15);
}

// bf16x2 helpers (packed pair in one u32; low ushort = even element)
__device__ __forceinline__ float bflo(u32 p) { return __uint_as_float(p << 16); }
__device__ __forceinline__ float bfhi(u32 p) { return __uint_as_float(p & 0xFFFF0000u); }
__device__ __forceinline__ u32 pack_bf16x2(float a, float b) {
    u32 ua = __float_as_uint(a);
    u32 ub = __float_as_uint(b);
    ua = (ua + 0x7FFFu + ((ua >> 16) & 1u)) >> 16;   // RNE
    ub = (ub + 0x7FFFu + ((ub >> 16) & 1u)) >> 16;
    return ua | (ub << 16);
}

// ---------------- init / epilogue ----------------

__global__ void lg_to_bf16(const float4* __restrict__ user, const float4* __restrict__ item,
                           uint2* __restrict__ dst, int user_vec4, int total_vec4) {
    int i = blockIdx.x * blockDim.x + threadIdx.x;
    if (i >= total_vec4) return;
    float4 v = (i < user_vec4) ? user[i] : item[i - user_vec4];
    dst[i] = make_uint2(pack_bf16x2(v.x, v.y), pack_bf16x2(v.z, v.w));
}

__global__ void lg_mean(const float4* __restrict__ user, const float4* __restrict__ item,
                        int user_vec4,
                        const uint2* __restrict__ e1, const uint2* __restrict__ e2,
                        const uint2* __restrict__ e3,
                        float4* __restrict__ out, int total_vec4) {
    int i = blockIdx.x * blockDim.x + threadIdx.x;
    if (i >= total_vec4) return;
    float4 a = (i < user_vec4) ? user[i] : item[i - user_vec4];
    uint2 b = e1[i], c = e2[i], d = e3[i];
    float4 r;
    r.x = (a.x + bflo(b.x) + bflo(c.x) + bflo(d.x)) * 0.25f;
    r.y = (a.y + bfhi(b.x) + bfhi(c.x) + bfhi(d.x)) * 0.25f;
    r.z = (a.z + bflo(b.y) + bflo(c.y) + bflo(d.y)) * 0.25f;
    r.w = (a.w + bfhi(b.y) + bfhi(c.y) + bfhi(d.y)) * 0.25f;
    out[i] = r;
}

// ---------------- CSR build: hist + scan ----------------

__global__ void lg_hist(const int* __restrict__ rows, int* __restrict__ counts, int nnz) {
    int e = blockIdx.x * blockDim.x + threadIdx.x;
    if (e >= nnz) return;
    atomicAdd(&counts[rows[e]], 1);
}

__global__ void lg_scan_reduce(const int* __restrict__ counts, int* __restrict__ partials, int n) {
    __shared__ int s[4];
    int base = blockIdx.x * SCAN_CHUNK;
    int sum = 0;
    for (int i = threadIdx.x; i < SCAN_CHUNK; i += 256) {
        int idx = base + i;
        if (idx < n) sum += counts[idx];
    }
    #pragma unroll
    for (int off = 32; off > 0; off >>= 1) sum += __shfl_xor(sum, off, 64);
    if ((threadIdx.x & 63) == 0) s[threadIdx.x >> 6] = sum;
    __syncthreads();
    if (threadIdx.x == 0) partials[blockIdx.x] = s[0] + s[1] + s[2] + s[3];
}

__global__ void lg_scan_partials(int* __restrict__ partials, int nb, int* __restrict__ offsets_end) {
    __shared__ int s[256];
    int t = threadIdx.x;
    int v = (t < nb) ? partials[t] : 0;
    s[t] = v;
    __syncthreads();
    #pragma unroll
    for (int off = 1; off < 256; off <<= 1) {
        int x = (t >= off) ? s[t - off] : 0;
        __syncthreads();
        s[t] += x;
        __syncthreads();
    }
    if (t < nb) partials[t] = s[t] - v;
    if (t == 255) *offsets_end = s[255];
}

__global__ void lg_scan_final(const int* __restrict__ counts, const int* __restrict__ partials,
                              int* __restrict__ offsets, int n) {
    __shared__ int s[256];
    int t = threadIdx.x;
    int base = blockIdx.x * SCAN_CHUNK + t * 4;
    int4 c = make_int4(0, 0, 0, 0);
    if (base + 3 < n) {
        c = *(const int4*)(counts + base);
    } else {
        if (base     < n) c.x = counts[base];
        if (base + 1 < n) c.y = counts[base + 1];
        if (base + 2 < n) c.z = counts[base + 2];
        if (base + 3 < n) c.w = counts[base + 3];
    }
    int tsum = c.x + c.y + c.z + c.w;
    s[t] = tsum;
    __syncthreads();
    #pragma unroll
    for (int off = 1; off < 256; off <<= 1) {
        int x = (t >= off) ? s[t - off] : 0;
        __syncthreads();
        s[t] += x;
        __syncthreads();
    }
    int excl = s[t] - tsum + partials[blockIdx.x];
    int4 o;
    o.x = excl;
    o.y = o.x + c.x;
    o.z = o.y + c.y;
    o.w = o.z + c.z;
    if (base + 3 < n) {
        *(int4*)(offsets + base) = o;
    } else {
        if (base     < n) offsets[base]     = o.x;
        if (base + 1 < n) offsets[base + 1] = o.y;
        if (base + 2 < n) offsets[base + 2] = o.z;
        if (base + 3 < n) offsets[base + 3] = o.w;
    }
}

__global__ void lg_scan1(const int* __restrict__ counts, int* __restrict__ offsets, int n) {
    const int T = 1024;
    int t = threadIdx.x;
    int chunk = (n + T - 1) / T;
    int start = t * chunk;
    int end = min(start + chunk, n);
    int sum = 0;
    for (int i = start; i < end; ++i) sum += counts[i];
    __shared__ int sdata[T];
    sdata[t] = sum;
    __syncthreads();
    #pragma unroll
    for (int off = 1; off < T; off <<= 1) {
        int v = (t >= off) ? sdata[t - off] : 0;
        __syncthreads();
        sdata[t] += v;
        __syncthreads();
    }
    int offset = sdata[t] - sum;
    for (int i = start; i < end; ++i) {
        int c = counts[i];
        offsets[i] = offset;
        offset += c;
    }
    if (t == T - 1) offsets[n] = sdata[T - 1];
}

// ---------------- two-level bucket sort ----------------

__global__ void lg_bucket_init(const int* __restrict__ offsets, int* __restrict__ bucketCursor,
                               int nbuck) {
    int b = blockIdx.x * blockDim.x + threadIdx.x;
    if (b >= nbuck) return;
    bucketCursor[b] = offsets[b << BUCKET_SHIFT];
}

// Pass A: coarse scatter into tmp, packed {localrow:8|col:24, val}.
// Regular stores (NOT nontemporal): same-block per-bucket runs are contiguous
// and merge to full lines in the writing XCD's L2 before writeback.
__global__ void lg_binA(const int* __restrict__ rows, const int* __restrict__ cols,
                        const float* __restrict__ vals, int* __restrict__ bucketCursor,
                        u64* __restrict__ tmp, int nnz, int nbuck) {
    __shared__ int hist[NBUCK_MAX];
    __shared__ int base[NBUCK_MAX];
    int tid = threadIdx.x;
    int bstart = blockIdx.x * BINA_CHUNK;
    int bend = min(bstart + BINA_CHUNK, nnz);

    for (int i = tid; i < nbuck; i += BINA_THREADS) hist[i] = 0;
    __syncthreads();
    for (int e = bstart + tid; e < bend; e += BINA_THREADS)
        atomicAdd(&hist[rows[e] >> BUCKET_SHIFT], 1);
    __syncthreads();
    for (int b = tid; b < nbuck; b += BINA_THREADS) {
        int c = hist[b];
        base[b] = (c > 0) ? atomicAdd(&bucketCursor[b], c) : 0;
        hist[b] = 0;   // reuse as local cursor
    }
    __syncthreads();
    for (int e = bstart + tid; e < bend; e += BINA_THREADS) {
        int r = rows[e];
        int b = r >> BUCKET_SHIFT;
        int pos = base[b] + atomicAdd(&hist[b], 1);
        u32 key = ((u32)(r & (ROWS_PER_BUCKET - 1)) << 24) | (u32)cols[e];
        u64 packed = (u64)key | ((u64)__float_as_uint(vals[e]) << 32);
        tmp[pos] = packed;
    }
}

// Pass B: one block per bucket; writes land in the bucket's contiguous CSR
// range (single CU -> single XCD L2 -> full-line writebacks).
__global__ void lg_binB(const int* __restrict__ offsets, const u64* __restrict__ tmp,
                        int2* __restrict__ edges, int n, int nbuck) {
    __shared__ int cursor[ROWS_PER_BUCKET];
    int bucket = blockIdx.x;
    int row0 = bucket << BUCKET_SHIFT;
    int tid = threadIdx.x;
    int r = row0 + tid;
    cursor[tid] = (r < n) ? offsets[r] : 0;
    __syncthreads();
    int bstart = offsets[row0];
    int bend = offsets[min(row0 + ROWS_PER_BUCKET, n)];
    for (int e = bstart + tid; e < bend; e += 256) {
        u64 p = tmp[e];
        u32 key = (u32)p;
        int lr = key >> 24;
        int col = (int)(key & 0xFFFFFFu);
        int pos = atomicAdd(&cursor[lr], 1);
        edges[pos] = make_int2(col, (int)(u32)(p >> 32));
    }
}

// Fallback fill (atomic scatter) if nbuck > NBUCK_MAX or ws too small.
__global__ void lg_fill(const int* __restrict__ rows, const int* __restrict__ cols,
                        const float* __restrict__ vals, int* __restrict__ cursor,
                        u64* __restrict__ edges, int nnz) {
    int e = blockIdx.x * blockDim.x + threadIdx.x;
    if (e >= nnz) return;
    int pos = atomicAdd(&cursor[rows[e]], 1);
    u64 packed = (u64)(u32)cols[e] | ((u64)__float_as_uint(vals[e]) << 32);
    edges[pos] = packed;
}

__global__ void lg_cursor_copy(const int* __restrict__ offsets, int* __restrict__ cursor, int n) {
    int i = blockIdx.x * blockDim.x + threadIdx.x;
    if (i < n) cursor[i] = offsets[i];
}

// ---------------- pull SpMM (bf16 gather, fp32 accumulate) ----------------

__global__ void lg_pull_bf16(const int* __restrict__ offs, const int2* __restrict__ edges,
                             const u32* __restrict__ src,   // bf16 table, N x 32 u32
                             u32* __restrict__ nxt, int n) {
    int row = blockIdx.x * (blockDim.x >> 6) + (threadIdx.x >> 6);
    if (row >= n) return;
    int lane = threadIdx.x & 63;
    int sub = lane >> 4;
    int q = lane & 15;

    int beg = offs[row];
    int end = offs[row + 1];
    float4 acc = make_float4(0.f, 0.f, 0.f, 0.f);

    int j = beg + sub;
    for (; j + 4 < end; j += 8) {
        int2 e0 = edges[j];
        int2 e1 = edges[j + 4];
        uint2 g0 = ((const uint2*)(src + (size_t)e0.x * 32))[q];
        uint2 g1 = ((const uint2*)(src + (size_t)e1.x * 32))[q];
        float v0 = __int_as_float(e0.y);
        float v1 = __int_as_float(e1.y);
        acc.x += v0 * bflo(g0.x) + v1 * bflo(g1.x);
        acc.y += v0 * bfhi(g0.x) + v1 * bfhi(g1.x);
        acc.z += v0 * bflo(g0.y) + v1 * bflo(g1.y);
        acc.w += v0 * bfhi(g0.y) + v1 * bfhi(g1.y);
    }
    for (; j < end; j += 4) {
        int2 e = edges[j];
        uint2 g = ((const uint2*)(src + (size_t)e.x * 32))[q];
        float v = __int_as_float(e.y);
        acc.x += v * bflo(g.x);
        acc.y += v * bfhi(g.x);
        acc.z += v * bflo(g.y);
        acc.w += v * bfhi(g.y);
    }

    acc.x += __shfl_xor(acc.x, 16, 64); acc.x += __shfl_xor(acc.x, 32, 64);
    acc.y += __shfl_xor(acc.y, 16, 64); acc.y += __shfl_xor(acc.y, 32, 64);
    acc.z += __shfl_xor(acc.z, 16, 64); acc.z += __shfl_xor(acc.z, 32, 64);
    acc.w += __shfl_xor(acc.w, 16, 64); acc.w += __shfl_xor(acc.w, 32, 64);

    float ss = acc.x * acc.x + acc.y * acc.y + acc.z * acc.z + acc.w * acc.w;
    #pragma unroll
    for (int off = 1; off < 16; off <<= 1) ss += __shfl_xor(ss, off, 64);
    float inv = 1.0f / fmaxf(sqrtf(ss), 1e-12f);

    if (sub == 0) {
        uint2 o = make_uint2(pack_bf16x2(acc.x * inv, acc.y * inv),
                             pack_bf16x2(acc.z * inv, acc.w * inv));
        ((uint2*)(nxt + (size_t)row * 32))[q] = o;
    }
}

// ---------------- fallback (atomic-scatter fp32 path) ----------------

__global__ void lg_init(const float4* __restrict__ user, const float4* __restrict__ item,
                        float4* __restrict__ cur, float4* __restrict__ sum,
                        int user_vec4, int total_vec4) {
    int i = blockIdx.x * blockDim.x + threadIdx.x;
    if (i >= total_vec4) return;
    float4 v = (i < user_vec4) ? user[i] : item[i - user_vec4];
    cur[i] = v;
    sum[i] = v;
}

__global__ void lg_scatter(const int* __restrict__ rows, const int* __restrict__ cols,
                           const float* __restrict__ vals,
                           const float* __restrict__ cur, float* __restrict__ next,
                           int nnz) {
    int gid = blockIdx.x * blockDim.x + threadIdx.x;
    int e = gid >> 6;
    int d = gid & 63;
    if (e >= nnz) return;
    atomicAdd(&next[rows[e] * D + d], vals[e] * cur[cols[e] * D + d]);
}

__global__ void lg_norm_acc(float* __restrict__ emb, float* __restrict__ sum, int n) {
    int row = blockIdx.x * (blockDim.x >> 6) + (threadIdx.x >> 6);
    int d = threadIdx.x & 63;
    if (row >= n) return;
    int idx = row * D + d;
    float v = emb[idx];
    float ss = v * v;
    #pragma unroll
    for (int off = 32; off > 0; off >>= 1) ss += __shfl_xor(ss, off, 64);
    float out = v / fmaxf(sqrtf(ss), 1e-12f);
    emb[idx] = out;
    sum[idx] += out;
}

__global__ void lg_final(float4* __restrict__ out, int n4) {
    int i = blockIdx.x * blockDim.x + threadIdx.x;
    if (i >= n4) return;
    float4 s = out[i];
    out[i] = make_float4(s.x * 0.25f, s.y * 0.25f, s.z * 0.25f, s.w * 0.25f);
}

// ---------------- launch ----------------

extern "C" void kernel_launch(void* const* d_in, const int* in_sizes, int n_in,
                              void* d_out, int out_size, void* d_ws, size_t ws_size,
                              hipStream_t stream) {
    const float* user = (const float*)d_in[0];
    const float* item = (const float*)d_in[1];
    const float* vals = (const float*)d_in[2];
    const int*   rows = (const int*)d_in[3];
    const int*   cols = (const int*)d_in[4];

    const int nU  = in_sizes[0] / D;
    const int nI  = in_sizes[1] / D;
    const int N   = nU + nI;
    const int nnz = in_sizes[2];

    const size_t embElems = (size_t)N * D;
    const size_t embU32   = (size_t)N * 32;
    const int total4 = (int)(embElems / 4);
    float* out = (float*)d_out;

    // ws layout
    char* p = (char*)d_ws;
    u32* t0  = (u32*)p;           p = align16(p + embU32 * sizeof(u32));
    u32* e1b = (u32*)p;           p = align16(p + embU32 * sizeof(u32));
    u32* e2b = (u32*)p;           p = align16(p + embU32 * sizeof(u32));
    u32* e3b = (u32*)p;           p = align16(p + embU32 * sizeof(u32));
    int* counts   = (int*)p;      p = align16(p + (size_t)N * sizeof(int));
    int* offsets  = (int*)p;      p = align16(p + (size_t)(N + 1) * sizeof(int));
    int* cursor   = (int*)p;      p = align16(p + (size_t)N * sizeof(int));
    int* partials = (int*)p;      p = align16(p + 256 * sizeof(int));
    int* bucketCursor = (int*)p;  p = align16(p + NBUCK_MAX * sizeof(int));
    u64* edges    = (u64*)p;      p = align16(p + (size_t)nnz * sizeof(u64));
    u64* tmp      = (u64*)p;      p = align16(p + (size_t)nnz * sizeof(u64));
    size_t needBytes = (size_t)(p - (char*)d_ws);
    size_t needNoTmp = needBytes - ((size_t)nnz * sizeof(u64) + 16);

    const int nbuck = (N + ROWS_PER_BUCKET - 1) / ROWS_PER_BUCKET;

    if (ws_size >= needNoTmp) {
        lg_to_bf16<<<(total4 + 255) / 256, 256, 0, stream>>>(
            (const float4*)user, (const float4*)item, (uint2*)t0, nU * D / 4, total4);

        // ---- hist + scan ----
        hipMemsetAsync(counts, 0, (size_t)N * sizeof(int), stream);
        int eb = (nnz + 255) / 256;
        lg_hist<<<eb, 256, 0, stream>>>(rows, counts, nnz);

        int nb = (N + SCAN_CHUNK - 1) / SCAN_CHUNK;
        if (nb <= 256) {
            lg_scan_reduce<<<nb, 256, 0, stream>>>(counts, partials, N);
            lg_scan_partials<<<1, 256, 0, stream>>>(partials, nb, offsets + N);
            lg_scan_final<<<nb, 256, 0, stream>>>(counts, partials, offsets, N);
        } else {
            lg_scan1<<<1, 1024, 0, stream>>>(counts, offsets, N);
        }

        // ---- edge sort ----
        if (nbuck <= NBUCK_MAX && ws_size >= needBytes) {
            lg_bucket_init<<<(nbuck + 255) / 256, 256, 0, stream>>>(offsets, bucketCursor, nbuck);
            int ab = (nnz + BINA_CHUNK - 1) / BINA_CHUNK;
            lg_binA<<<ab, BINA_THREADS, 0, stream>>>(rows, cols, vals, bucketCursor, tmp, nnz, nbuck);
            lg_binB<<<nbuck, 256, 0, stream>>>(offsets, tmp, (int2*)edges, N, nbuck);
        } else {
            lg_cursor_copy<<<(N + 255) / 256, 256, 0, stream>>>(offsets, cursor, N);
            lg_fill<<<eb, 256, 0, stream>>>(rows, cols, vals, cursor, edges, nnz);
        }

        // ---- 3 bf16 pulls ----
        int rb = (N + 3) / 4;
        lg_pull_bf16<<<rb, 256, 0, stream>>>(offsets, (const int2*)edges, t0,  e1b, N);
        lg_pull_bf16<<<rb, 256, 0, stream>>>(offsets, (const int2*)edges, e1b, e2b, N);
        lg_pull_bf16<<<rb, 256, 0, stream>>>(offsets, (const int2*)edges, e2b, e3b, N);

        // ---- epilogue ----
        lg_mean<<<(total4 + 255) / 256, 256, 0, stream>>>(
            (const float4*)user, (const float4*)item, nU * D / 4,
            (const uint2*)e1b, (const uint2*)e2b, (const uint2*)e3b,
            (float4*)out, total4);
    } else {
        // fallback: fp32 atomic scatter
        float* buf0 = (float*)t0;
        float* buf1 = buf0 + embElems;
        float* sum  = out;
        lg_init<<<(total4 + 255) / 256, 256, 0, stream>>>(
            (const float4*)user, (const float4*)item,
            (float4*)buf0, (float4*)sum, nU * D / 4, total4);
        float* cur = buf0;
        float* nxt = buf1;
        for (int layer = 0; layer < 3; ++layer) {
            hipMemsetAsync(nxt, 0, embElems * sizeof(float), stream);
            int totThreads = nnz * 64;
            int blocks = (totThreads + 255) / 256;
            lg_scatter<<<blocks, 256, 0, stream>>>(rows, cols, vals, cur, nxt, nnz);
            lg_norm_acc<<<(N + 3) / 4, 256, 0, stream>>>(nxt, sum, N);
            float* t = cur; cur = nxt; nxt = t;
        }
        lg_final<<<(total4 + 255) / 256, 256, 0, stream>>>((float4*)sum, total4);
    }
}

// Round 8
// 443.904 us; speedup vs baseline: 4.0002x; 1.1825x over previous
//
#include <hip/hip_runtime.h>

#define D 64
#define SCAN_CHUNK 1024
#define BUCKET_SHIFT 8
#define ROWS_PER_BUCKET 256
#define NBUCK_MAX 1024
#define BINA_CHUNK 8192
#define BINA_THREADS 512
#define BHIST_CHUNK 16384
#define BHIST_THREADS 512

typedef unsigned int u32;
typedef unsigned long long u64;

static inline char* align16(char* p) {
    return (char*)(((uintptr_t)p + 15) & ~(uintptr_t)15);
}

// bf16x2 helpers (packed pair in one u32; low ushort = even element)
__device__ __forceinline__ float bflo(u32 p) { return __uint_as_float(p << 16); }
__device__ __forceinline__ float bfhi(u32 p) { return __uint_as_float(p & 0xFFFF0000u); }
__device__ __forceinline__ u32 pack_bf16x2(float a, float b) {
    u32 ua = __float_as_uint(a);
    u32 ub = __float_as_uint(b);
    ua = (ua + 0x7FFFu + ((ua >> 16) & 1u)) >> 16;   // RNE
    ub = (ub + 0x7FFFu + ((ub >> 16) & 1u)) >> 16;
    return ua | (ub << 16);
}

// ---------------- init / epilogue ----------------

__global__ void lg_to_bf16(const float4* __restrict__ user, const float4* __restrict__ item,
                           uint2* __restrict__ dst, int user_vec4, int total_vec4) {
    int i = blockIdx.x * blockDim.x + threadIdx.x;
    if (i >= total_vec4) return;
    float4 v = (i < user_vec4) ? user[i] : item[i - user_vec4];
    dst[i] = make_uint2(pack_bf16x2(v.x, v.y), pack_bf16x2(v.z, v.w));
}

__global__ void lg_mean(const float4* __restrict__ user, const float4* __restrict__ item,
                        int user_vec4,
                        const uint2* __restrict__ e1, const uint2* __restrict__ e2,
                        const uint2* __restrict__ e3,
                        float4* __restrict__ out, int total_vec4) {
    int i = blockIdx.x * blockDim.x + threadIdx.x;
    if (i >= total_vec4) return;
    float4 a = (i < user_vec4) ? user[i] : item[i - user_vec4];
    uint2 b = e1[i], c = e2[i], d = e3[i];
    float4 r;
    r.x = (a.x + bflo(b.x) + bflo(c.x) + bflo(d.x)) * 0.25f;
    r.y = (a.y + bfhi(b.x) + bfhi(c.x) + bfhi(d.x)) * 0.25f;
    r.z = (a.z + bflo(b.y) + bflo(c.y) + bflo(d.y)) * 0.25f;
    r.w = (a.w + bfhi(b.y) + bfhi(c.y) + bfhi(d.y)) * 0.25f;
    out[i] = r;
}

// ---------------- bucket-level histogram + scan ----------------

// Per-block LDS histogram over buckets (row>>8); ~nbuck global atomics/block.
__global__ void lg_bhist(const int* __restrict__ rows, int* __restrict__ bcounts,
                         int nnz, int nbuck) {
    __shared__ int h[NBUCK_MAX];
    int tid = threadIdx.x;
    int bstart = blockIdx.x * BHIST_CHUNK;
    int bend = min(bstart + BHIST_CHUNK, nnz);
    for (int i = tid; i < nbuck; i += BHIST_THREADS) h[i] = 0;
    __syncthreads();
    for (int e = bstart + tid; e < bend; e += BHIST_THREADS)
        atomicAdd(&h[rows[e] >> BUCKET_SHIFT], 1);
    __syncthreads();
    for (int b = tid; b < nbuck; b += BHIST_THREADS) {
        int c = h[b];
        if (c > 0) atomicAdd(&bcounts[b], c);
    }
}

// Single-block exclusive scan of bucket counts (nbuck <= 1024).
// Seeds bucketOffs and binA's bucketCursor; writes offsets[N] = nnz.
__global__ void lg_bscan(const int* __restrict__ bcounts, int* __restrict__ bucketOffs,
                         int* __restrict__ bucketCursor, int* __restrict__ offsets_end,
                         int nbuck, int nnz) {
    __shared__ int s[1024];
    int t = threadIdx.x;
    int v = (t < nbuck) ? bcounts[t] : 0;
    s[t] = v;
    __syncthreads();
    #pragma unroll
    for (int off = 1; off < 1024; off <<= 1) {
        int x = (t >= off) ? s[t - off] : 0;
        __syncthreads();
        s[t] += x;
        __syncthreads();
    }
    if (t < nbuck) {
        int excl = s[t] - v;
        bucketOffs[t] = excl;
        bucketCursor[t] = excl;
    }
    if (t == 0) {
        bucketOffs[nbuck] = nnz;
        *offsets_end = nnz;
    }
}

// ---------------- two-level bucket sort ----------------

// Pass A: coarse scatter into tmp, packed {localrow:8|col:24, val}.
// Regular stores: same-block per-bucket runs merge to full lines in L2.
__global__ void lg_binA(const int* __restrict__ rows, const int* __restrict__ cols,
                        const float* __restrict__ vals, int* __restrict__ bucketCursor,
                        u64* __restrict__ tmp, int nnz, int nbuck) {
    __shared__ int hist[NBUCK_MAX];
    __shared__ int base[NBUCK_MAX];
    int tid = threadIdx.x;
    int bstart = blockIdx.x * BINA_CHUNK;
    int bend = min(bstart + BINA_CHUNK, nnz);

    for (int i = tid; i < nbuck; i += BINA_THREADS) hist[i] = 0;
    __syncthreads();
    for (int e = bstart + tid; e < bend; e += BINA_THREADS)
        atomicAdd(&hist[rows[e] >> BUCKET_SHIFT], 1);
    __syncthreads();
    for (int b = tid; b < nbuck; b += BINA_THREADS) {
        int c = hist[b];
        base[b] = (c > 0) ? atomicAdd(&bucketCursor[b], c) : 0;
        hist[b] = 0;   // reuse as local cursor
    }
    __syncthreads();
    for (int e = bstart + tid; e < bend; e += BINA_THREADS) {
        int r = rows[e];
        int b = r >> BUCKET_SHIFT;
        int pos = base[b] + atomicAdd(&hist[b], 1);
        u32 key = ((u32)(r & (ROWS_PER_BUCKET - 1)) << 24) | (u32)cols[e];
        u64 packed = (u64)key | ((u64)__float_as_uint(vals[e]) << 32);
        tmp[pos] = packed;
    }
}

// Pass B2: one block per bucket. Builds the per-row histogram from tmp keys
// in LDS, scans it to produce the final per-row CSR offsets (written to
// global for the pulls), then scatters edges into CSR order.
__global__ void lg_binB2(const int* __restrict__ bucketOffs, const u64* __restrict__ tmp,
                         int* __restrict__ offsets, int2* __restrict__ edges, int n) {
    __shared__ int h[ROWS_PER_BUCKET];
    __shared__ int s[ROWS_PER_BUCKET];
    __shared__ int cur[ROWS_PER_BUCKET];
    int bucket = blockIdx.x;
    int row0 = bucket << BUCKET_SHIFT;
    int tid = threadIdx.x;
    int bstart = bucketOffs[bucket];
    int bend = bucketOffs[bucket + 1];

    h[tid] = 0;
    __syncthreads();
    for (int e = bstart + tid; e < bend; e += 256)
        atomicAdd(&h[(u32)((u32)tmp[e]) >> 24], 1);
    __syncthreads();
    int v = h[tid];
    s[tid] = v;
    __syncthreads();
    #pragma unroll
    for (int off = 1; off < 256; off <<= 1) {
        int x = (tid >= off) ? s[tid - off] : 0;
        __syncthreads();
        s[tid] += x;
        __syncthreads();
    }
    int rowOff = bstart + s[tid] - v;   // absolute CSR offset of this row
    int r = row0 + tid;
    if (r < n) offsets[r] = rowOff;
    cur[tid] = rowOff;
    __syncthreads();
    for (int e = bstart + tid; e < bend; e += 256) {
        u64 p = tmp[e];
        u32 key = (u32)p;
        int lr = key >> 24;
        int col = (int)(key & 0xFFFFFFu);
        int pos = atomicAdd(&cur[lr], 1);
        edges[pos] = make_int2(col, (int)(u32)(p >> 32));
    }
}

// ---------------- fallback CSR build (nbuck > NBUCK_MAX) ----------------

__global__ void lg_hist(const int* __restrict__ rows, int* __restrict__ counts, int nnz) {
    int e = blockIdx.x * blockDim.x + threadIdx.x;
    if (e >= nnz) return;
    atomicAdd(&counts[rows[e]], 1);
}

__global__ void lg_scan1(const int* __restrict__ counts, int* __restrict__ offsets,
                         int* __restrict__ cursor, int n) {
    const int T = 1024;
    int t = threadIdx.x;
    int chunk = (n + T - 1) / T;
    int start = t * chunk;
    int end = min(start + chunk, n);
    int sum = 0;
    for (int i = start; i < end; ++i) sum += counts[i];
    __shared__ int sdata[T];
    sdata[t] = sum;
    __syncthreads();
    #pragma unroll
    for (int off = 1; off < T; off <<= 1) {
        int v = (t >= off) ? sdata[t - off] : 0;
        __syncthreads();
        sdata[t] += v;
        __syncthreads();
    }
    int offset = sdata[t] - sum;
    for (int i = start; i < end; ++i) {
        int c = counts[i];
        offsets[i] = offset;
        cursor[i] = offset;
        offset += c;
    }
    if (t == T - 1) offsets[n] = sdata[T - 1];
}

__global__ void lg_fill(const int* __restrict__ rows, const int* __restrict__ cols,
                        const float* __restrict__ vals, int* __restrict__ cursor,
                        u64* __restrict__ edges, int nnz) {
    int e = blockIdx.x * blockDim.x + threadIdx.x;
    if (e >= nnz) return;
    int pos = atomicAdd(&cursor[rows[e]], 1);
    u64 packed = (u64)(u32)cols[e] | ((u64)__float_as_uint(vals[e]) << 32);
    edges[pos] = packed;
}

// ---------------- pull SpMM (bf16 gather, fp32 accumulate) ----------------

__global__ void lg_pull_bf16(const int* __restrict__ offs, const int2* __restrict__ edges,
                             const u32* __restrict__ src,   // bf16 table, N x 32 u32
                             u32* __restrict__ nxt, int n) {
    int row = blockIdx.x * (blockDim.x >> 6) + (threadIdx.x >> 6);
    if (row >= n) return;
    int lane = threadIdx.x & 63;
    int sub = lane >> 4;
    int q = lane & 15;

    int beg = offs[row];
    int end = offs[row + 1];
    float4 acc = make_float4(0.f, 0.f, 0.f, 0.f);

    int j = beg + sub;
    for (; j + 4 < end; j += 8) {
        int2 e0 = edges[j];
        int2 e1 = edges[j + 4];
        uint2 g0 = ((const uint2*)(src + (size_t)e0.x * 32))[q];
        uint2 g1 = ((const uint2*)(src + (size_t)e1.x * 32))[q];
        float v0 = __int_as_float(e0.y);
        float v1 = __int_as_float(e1.y);
        acc.x += v0 * bflo(g0.x) + v1 * bflo(g1.x);
        acc.y += v0 * bfhi(g0.x) + v1 * bfhi(g1.x);
        acc.z += v0 * bflo(g0.y) + v1 * bflo(g1.y);
        acc.w += v0 * bfhi(g0.y) + v1 * bfhi(g1.y);
    }
    for (; j < end; j += 4) {
        int2 e = edges[j];
        uint2 g = ((const uint2*)(src + (size_t)e.x * 32))[q];
        float v = __int_as_float(e.y);
        acc.x += v * bflo(g.x);
        acc.y += v * bfhi(g.x);
        acc.z += v * bflo(g.y);
        acc.w += v * bfhi(g.y);
    }

    acc.x += __shfl_xor(acc.x, 16, 64); acc.x += __shfl_xor(acc.x, 32, 64);
    acc.y += __shfl_xor(acc.y, 16, 64); acc.y += __shfl_xor(acc.y, 32, 64);
    acc.z += __shfl_xor(acc.z, 16, 64); acc.z += __shfl_xor(acc.z, 32, 64);
    acc.w += __shfl_xor(acc.w, 16, 64); acc.w += __shfl_xor(acc.w, 32, 64);

    float ss = acc.x * acc.x + acc.y * acc.y + acc.z * acc.z + acc.w * acc.w;
    #pragma unroll
    for (int off = 1; off < 16; off <<= 1) ss += __shfl_xor(ss, off, 64);
    float inv = 1.0f / fmaxf(sqrtf(ss), 1e-12f);

    if (sub == 0) {
        uint2 o = make_uint2(pack_bf16x2(acc.x * inv, acc.y * inv),
                             pack_bf16x2(acc.z * inv, acc.w * inv));
        ((uint2*)(nxt + (size_t)row * 32))[q] = o;
    }
}

// ---------------- fallback (atomic-scatter fp32 path) ----------------

__global__ void lg_init(const float4* __restrict__ user, const float4* __restrict__ item,
                        float4* __restrict__ cur, float4* __restrict__ sum,
                        int user_vec4, int total_vec4) {
    int i = blockIdx.x * blockDim.x + threadIdx.x;
    if (i >= total_vec4) return;
    float4 v = (i < user_vec4) ? user[i] : item[i - user_vec4];
    cur[i] = v;
    sum[i] = v;
}

__global__ void lg_scatter(const int* __restrict__ rows, const int* __restrict__ cols,
                           const float* __restrict__ vals,
                           const float* __restrict__ cur, float* __restrict__ next,
                           int nnz) {
    int gid = blockIdx.x * blockDim.x + threadIdx.x;
    int e = gid >> 6;
    int d = gid & 63;
    if (e >= nnz) return;
    atomicAdd(&next[rows[e] * D + d], vals[e] * cur[cols[e] * D + d]);
}

__global__ void lg_norm_acc(float* __restrict__ emb, float* __restrict__ sum, int n) {
    int row = blockIdx.x * (blockDim.x >> 6) + (threadIdx.x >> 6);
    int d = threadIdx.x & 63;
    if (row >= n) return;
    int idx = row * D + d;
    float v = emb[idx];
    float ss = v * v;
    #pragma unroll
    for (int off = 32; off > 0; off >>= 1) ss += __shfl_xor(ss, off, 64);
    float out = v / fmaxf(sqrtf(ss), 1e-12f);
    emb[idx] = out;
    sum[idx] += out;
}

__global__ void lg_final(float4* __restrict__ out, int n4) {
    int i = blockIdx.x * blockDim.x + threadIdx.x;
    if (i >= n4) return;
    float4 s = out[i];
    out[i] = make_float4(s.x * 0.25f, s.y * 0.25f, s.z * 0.25f, s.w * 0.25f);
}

// ---------------- launch ----------------

extern "C" void kernel_launch(void* const* d_in, const int* in_sizes, int n_in,
                              void* d_out, int out_size, void* d_ws, size_t ws_size,
                              hipStream_t stream) {
    const float* user = (const float*)d_in[0];
    const float* item = (const float*)d_in[1];
    const float* vals = (const float*)d_in[2];
    const int*   rows = (const int*)d_in[3];
    const int*   cols = (const int*)d_in[4];

    const int nU  = in_sizes[0] / D;
    const int nI  = in_sizes[1] / D;
    const int N   = nU + nI;
    const int nnz = in_sizes[2];

    const size_t embElems = (size_t)N * D;
    const size_t embU32   = (size_t)N * 32;
    const int total4 = (int)(embElems / 4);
    float* out = (float*)d_out;

    // ws layout
    char* p = (char*)d_ws;
    u32* t0  = (u32*)p;           p = align16(p + embU32 * sizeof(u32));
    u32* e1b = (u32*)p;           p = align16(p + embU32 * sizeof(u32));
    u32* e2b = (u32*)p;           p = align16(p + embU32 * sizeof(u32));
    u32* e3b = (u32*)p;           p = align16(p + embU32 * sizeof(u32));
    int* counts   = (int*)p;      p = align16(p + (size_t)N * sizeof(int));     // fallback only
    int* offsets  = (int*)p;      p = align16(p + (size_t)(N + 1) * sizeof(int));
    int* cursor   = (int*)p;      p = align16(p + (size_t)N * sizeof(int));     // fallback only
    int* bcounts  = (int*)p;      p = align16(p + NBUCK_MAX * sizeof(int));
    int* bucketOffs = (int*)p;    p = align16(p + (NBUCK_MAX + 1) * sizeof(int));
    int* bucketCursor = (int*)p;  p = align16(p + NBUCK_MAX * sizeof(int));
    u64* edges    = (u64*)p;      p = align16(p + (size_t)nnz * sizeof(u64));
    u64* tmp      = (u64*)p;      p = align16(p + (size_t)nnz * sizeof(u64));
    size_t needBytes = (size_t)(p - (char*)d_ws);
    size_t needNoTmp = needBytes - ((size_t)nnz * sizeof(u64) + 16);

    const int nbuck = (N + ROWS_PER_BUCKET - 1) / ROWS_PER_BUCKET;

    if (ws_size >= needNoTmp) {
        lg_to_bf16<<<(total4 + 255) / 256, 256, 0, stream>>>(
            (const float4*)user, (const float4*)item, (uint2*)t0, nU * D / 4, total4);

        if (nbuck <= NBUCK_MAX && ws_size >= needBytes) {
            // ---- bucket-level hist + scan (no per-row global atomics) ----
            hipMemsetAsync(bcounts, 0, (size_t)nbuck * sizeof(int), stream);
            int hb = (nnz + BHIST_CHUNK - 1) / BHIST_CHUNK;
            lg_bhist<<<hb, BHIST_THREADS, 0, stream>>>(rows, bcounts, nnz, nbuck);
            lg_bscan<<<1, 1024, 0, stream>>>(bcounts, bucketOffs, bucketCursor,
                                             offsets + N, nbuck, nnz);
            // ---- two-level sort; binB2 also emits per-row offsets ----
            int ab = (nnz + BINA_CHUNK - 1) / BINA_CHUNK;
            lg_binA<<<ab, BINA_THREADS, 0, stream>>>(rows, cols, vals, bucketCursor,
                                                     tmp, nnz, nbuck);
            lg_binB2<<<nbuck, 256, 0, stream>>>(bucketOffs, tmp, offsets, (int2*)edges, N);
        } else {
            // ---- fallback CSR build ----
            hipMemsetAsync(counts, 0, (size_t)N * sizeof(int), stream);
            int eb = (nnz + 255) / 256;
            lg_hist<<<eb, 256, 0, stream>>>(rows, counts, nnz);
            lg_scan1<<<1, 1024, 0, stream>>>(counts, offsets, cursor, N);
            lg_fill<<<eb, 256, 0, stream>>>(rows, cols, vals, cursor, edges, nnz);
        }

        // ---- 3 bf16 pulls ----
        int rb = (N + 3) / 4;
        lg_pull_bf16<<<rb, 256, 0, stream>>>(offsets, (const int2*)edges, t0,  e1b, N);
        lg_pull_bf16<<<rb, 256, 0, stream>>>(offsets, (const int2*)edges, e1b, e2b, N);
        lg_pull_bf16<<<rb, 256, 0, stream>>>(offsets, (const int2*)edges, e2b, e3b, N);

        // ---- epilogue ----
        lg_mean<<<(total4 + 255) / 256, 256, 0, stream>>>(
            (const float4*)user, (const float4*)item, nU * D / 4,
            (const uint2*)e1b, (const uint2*)e2b, (const uint2*)e3b,
            (float4*)out, total4);
    } else {
        // fallback: fp32 atomic scatter
        float* buf0 = (float*)t0;
        float* buf1 = buf0 + embElems;
        float* sum  = out;
        lg_init<<<(total4 + 255) / 256, 256, 0, stream>>>(
            (const float4*)user, (const float4*)item,
            (float4*)buf0, (float4*)sum, nU * D / 4, total4);
        float* cur = buf0;
        float* nxt = buf1;
        for (int layer = 0; layer < 3; ++layer) {
            hipMemsetAsync(nxt, 0, embElems * sizeof(float), stream);
            int totThreads = nnz * 64;
            int blocks = (totThreads + 255) / 256;
            lg_scatter<<<blocks, 256, 0, stream>>>(rows, cols, vals, cur, nxt, nnz);
            lg_norm_acc<<<(N + 3) / 4, 256, 0, stream>>>(nxt, sum, N);
            float* t = cur; cur = nxt; nxt = t;
        }
        lg_final<<<(total4 + 255) / 256, 256, 0, stream>>>((float4*)sum, total4);
    }
}